// Round 8
// baseline (351.703 us; speedup 1.0000x reference)
//
#include <hip/hip_runtime.h>
#include <math.h>

#define D_MODEL 512
#define SEQ     2048
#define BATCH   4
#define NH      8
#define HD      64
#define CHUNK   32
#define NCHUNK  64
#define M_TOK   (BATCH*SEQ)   // 8192

typedef __attribute__((ext_vector_type(8))) short bhalf8;   // 8 bf16 = 4 VGPR
typedef __attribute__((ext_vector_type(4))) float f32x4;

__device__ __forceinline__ float sigmoidf_(float x){ return 1.f/(1.f+expf(-x)); }

__device__ __forceinline__ unsigned short f2b(float f){   // fp32 -> bf16 RNE
  unsigned u = __float_as_uint(f);
  u += 0x7FFFu + ((u>>16)&1u);
  return (unsigned short)(u>>16);
}

__device__ __forceinline__ void gll16(const void* g, void* l){
  __builtin_amdgcn_global_load_lds(
      (const __attribute__((address_space(1))) unsigned int*)g,
      (__attribute__((address_space(3))) unsigned int*)l, 16, 0, 0);
}

__device__ __forceinline__ float exp2_hw(float x){
  float r;
  asm volatile("v_exp_f32 %0, %1" : "=v"(r) : "v"(x));
  return r;
}

// ---------- block reduction (blockDim up to 512) ----------
__device__ __forceinline__ float block_sum(float v, float* lds){
  #pragma unroll
  for (int o=32;o>0;o>>=1) v += __shfl_xor(v,o);
  int w = threadIdx.x>>6, l = threadIdx.x&63;
  if (l==0) lds[w]=v;
  __syncthreads();
  float t=0.f; int nw = blockDim.x>>6;
  for (int i=0;i<nw;++i) t+=lds[i];
  __syncthreads();
  return t;
}

// ---------- all weight converts in one launch ----------
__global__ void cvtall_k(const float* __restrict__ s0,const float* __restrict__ s1,
                         const float* __restrict__ s2,const float* __restrict__ s3,
                         const float* __restrict__ s4,const float* __restrict__ s5,
                         unsigned short* __restrict__ d0,unsigned short* __restrict__ d1,
                         unsigned short* __restrict__ d2,unsigned short* __restrict__ d3,
                         unsigned short* __restrict__ d4,unsigned short* __restrict__ d5){
  int j = blockIdx.x*blockDim.x + threadIdx.x;
  const float* s; unsigned short* d;
  if (j < 196608){ s=s0; d=d0; }
  else if ((j-=196608) < 65536){ s=s1; d=d1; }
  else if ((j-=65536)  < 65536){ s=s2; d=d2; }
  else if ((j-=65536)  < 65536){ s=s3; d=d3; }
  else if ((j-=65536)  < 262144){ s=s4; d=d4; }
  else if ((j-=262144) < 262144){ s=s5; d=d5; }
  else return;
  float4 v = ((const float4*)s)[j];
  unsigned a=f2b(v.x), b=f2b(v.y), c=f2b(v.z), e=f2b(v.w);
  uint2 p; p.x = a | (b<<16); p.y = c | (e<<16);
  ((uint2*)d)[j] = p;
}

// ---------- shift: fp32 out + bf16 out ----------
__global__ void shift2_k(const float* __restrict__ x, const float* __restrict__ xp,
                         const float* __restrict__ mu, float* __restrict__ of,
                         unsigned short* __restrict__ ob, int n4){
  int i = blockIdx.x*blockDim.x + threadIdx.x;
  if (i < n4){
    float m = mu[0];
    float4 a = ((const float4*)x)[i], p = ((const float4*)xp)[i];
    float4 r;
    r.x = m*a.x + (1.f-m)*p.x; r.y = m*a.y + (1.f-m)*p.y;
    r.z = m*a.z + (1.f-m)*p.z; r.w = m*a.w + (1.f-m)*p.w;
    ((float4*)of)[i] = r;
    unsigned A=f2b(r.x), B=f2b(r.y), C=f2b(r.z), E=f2b(r.w);
    uint2 q; q.x = A | (B<<16); q.y = C | (E<<16);
    ((uint2*)ob)[i] = q;
  }
}

// ---------- bf16 MFMA GEMM 128x128 (verified) ----------
template<int ACT, int OUTB>
__global__ __launch_bounds__(256) void mgemm_k(const unsigned short* __restrict__ A,
    const unsigned short* __restrict__ W, const float* __restrict__ bias,
    float* __restrict__ Yf, unsigned short* __restrict__ Yb, int Nd, int K){
  __shared__ unsigned short As[128*64];
  __shared__ unsigned short Bs[128*64];
  const int tid = threadIdx.x;
  const int w = tid>>6, lane = tid&63;
  const int l15 = lane&15, l4 = lane>>4;
  const int wr = w>>1, wc = w&1;
  const int bn = blockIdx.x, bm = blockIdx.y;

  const size_t Kb = (size_t)K*2;
  const int srow  = lane>>3;
  const int sbyte = ((lane&7)*16) ^ (srow<<4);
  const char* Ag = (const char*)A + (size_t)(bm*128)*Kb + sbyte;
  const char* Wg = (const char*)W + (size_t)(bn*128)*Kb + sbyte;

  f32x4 acc[4][4];
  const f32x4 z = {0.f,0.f,0.f,0.f};
  #pragma unroll
  for (int i=0;i<4;++i)
    #pragma unroll
    for (int j=0;j<4;++j) acc[i][j] = z;

  const int KT = K/64;
  for (int kt=0; kt<KT; ++kt){
    if (kt) __syncthreads();
    const size_t kOff = (size_t)kt*128;
    #pragma unroll
    for (int i=0;i<4;++i){
      int c = w*4 + i;
      int r = c*8 + srow;
      gll16(Ag + (size_t)r*Kb + kOff, (char*)As + c*1024);
      gll16(Wg + (size_t)r*Kb + kOff, (char*)Bs + c*1024);
    }
    __syncthreads();

    bhalf8 af[4][2], bf_[4][2];
    #pragma unroll
    for (int fr=0; fr<4; ++fr){
      int row = wr*64 + fr*16 + l15;
      #pragma unroll
      for (int ks=0; ks<2; ++ks){
        int byo = (l4*16 + ks*64) ^ ((row&7)<<4);
        af[fr][ks] = *(const bhalf8*)((const char*)As + row*128 + byo);
      }
    }
    #pragma unroll
    for (int fc=0; fc<4; ++fc){
      int row = wc*64 + fc*16 + l15;
      #pragma unroll
      for (int ks=0; ks<2; ++ks){
        int byo = (l4*16 + ks*64) ^ ((row&7)<<4);
        bf_[fc][ks] = *(const bhalf8*)((const char*)Bs + row*128 + byo);
      }
    }
    #pragma unroll
    for (int ks=0; ks<2; ++ks)
      #pragma unroll
      for (int fr=0; fr<4; ++fr)
        #pragma unroll
        for (int fc=0; fc<4; ++fc)
          acc[fr][fc] = __builtin_amdgcn_mfma_f32_16x16x32_bf16(af[fr][ks], bf_[fc][ks], acc[fr][fc], 0, 0, 0);
  }

  const int rowBase = bm*128 + wr*64;
  const int colBase = bn*128 + wc*64;
  #pragma unroll
  for (int fc=0; fc<4; ++fc){
    int col = colBase + fc*16 + l15;
    float bv = bias[col];
    #pragma unroll
    for (int fr=0; fr<4; ++fr){
      #pragma unroll
      for (int j=0; j<4; ++j){
        int row = rowBase + fr*16 + l4*4 + j;
        float v = acc[fr][fc][j] + bv;
        if (ACT) v = fmaxf(v, 0.f);
        if (OUTB) Yb[(size_t)row*Nd + col] = f2b(v);
        else      Yf[(size_t)row*Nd + col] = v;
      }
    }
  }
}

// ---------- bf16 MFMA GEMM 128x64 (N=512 shapes) ----------
// FUSE2: blockIdx.x in [0,16): bn>=8 selects {W1v,bias1,Y1}.
template<int ACT, int FUSE2>
__global__ __launch_bounds__(256) void mgemm64_k(const unsigned short* __restrict__ A,
    const unsigned short* __restrict__ W0, const unsigned short* __restrict__ W1v,
    const float* __restrict__ bias0, const float* __restrict__ bias1,
    float* __restrict__ Y0, float* __restrict__ Y1, int Nd, int K){
  __shared__ unsigned short As[128*64];
  __shared__ unsigned short Bs[64*64];
  const int tid = threadIdx.x;
  const int w = tid>>6, lane = tid&63;
  const int l15 = lane&15, l4 = lane>>4;
  const int wr = w>>1, wc = w&1;
  int bn = blockIdx.x;
  const int bm = blockIdx.y;
  const unsigned short* W = W0;
  const float* bias = bias0;
  float* Yf = Y0;
  if (FUSE2 && bn >= 8){ W = W1v; bias = bias1; Yf = Y1; bn -= 8; }

  const size_t Kb = (size_t)K*2;
  const int srow  = lane>>3;
  const int sbyte = ((lane&7)*16) ^ (srow<<4);
  const char* Ag = (const char*)A + (size_t)(bm*128)*Kb + sbyte;
  const char* Wg = (const char*)W + (size_t)(bn*64)*Kb + sbyte;

  f32x4 acc[4][2];
  const f32x4 z = {0.f,0.f,0.f,0.f};
  #pragma unroll
  for (int i=0;i<4;++i)
    #pragma unroll
    for (int j=0;j<2;++j) acc[i][j] = z;

  const int KT = K/64;
  for (int kt=0; kt<KT; ++kt){
    if (kt) __syncthreads();
    const size_t kOff = (size_t)kt*128;
    #pragma unroll
    for (int i=0;i<4;++i){
      int c = w*4 + i;
      int r = c*8 + srow;
      gll16(Ag + (size_t)r*Kb + kOff, (char*)As + c*1024);
    }
    #pragma unroll
    for (int i=0;i<2;++i){
      int c = w*2 + i;
      int r = c*8 + srow;
      gll16(Wg + (size_t)r*Kb + kOff, (char*)Bs + c*1024);
    }
    __syncthreads();

    bhalf8 af[4][2], bf_[2][2];
    #pragma unroll
    for (int fr=0; fr<4; ++fr){
      int row = wr*64 + fr*16 + l15;
      #pragma unroll
      for (int ks=0; ks<2; ++ks){
        int byo = (l4*16 + ks*64) ^ ((row&7)<<4);
        af[fr][ks] = *(const bhalf8*)((const char*)As + row*128 + byo);
      }
    }
    #pragma unroll
    for (int fc=0; fc<2; ++fc){
      int row = wc*32 + fc*16 + l15;
      #pragma unroll
      for (int ks=0; ks<2; ++ks){
        int byo = (l4*16 + ks*64) ^ ((row&7)<<4);
        bf_[fc][ks] = *(const bhalf8*)((const char*)Bs + row*128 + byo);
      }
    }
    #pragma unroll
    for (int ks=0; ks<2; ++ks)
      #pragma unroll
      for (int fr=0; fr<4; ++fr)
        #pragma unroll
        for (int fc=0; fc<2; ++fc)
          acc[fr][fc] = __builtin_amdgcn_mfma_f32_16x16x32_bf16(af[fr][ks], bf_[fc][ks], acc[fr][fc], 0, 0, 0);
  }

  const int rowBase = bm*128 + wr*64;
  const int colBase = bn*64 + wc*32;
  #pragma unroll
  for (int fc=0; fc<2; ++fc){
    int col = colBase + fc*16 + l15;
    float bv = bias[col];
    #pragma unroll
    for (int fr=0; fr<4; ++fr){
      #pragma unroll
      for (int j=0; j<4; ++j){
        int row = rowBase + fr*16 + l4*4 + j;
        float v = acc[fr][fc][j] + bv;
        if (ACT) v = fmaxf(v, 0.f);
        Yf[(size_t)row*Nd + col] = v;
      }
    }
  }
}

// ---------- bf16 MFMA flash attention: QBLK=64, 4 waves, grid 1024 ----------
// block = (qt, h, b); wave w owns q rows qt*64 + w*16 + [0,16).
// Swapped QK: S^T via mfma(K,Q) -> lane holds S[kv=fc*16+l4*4+j][q=l15].
// exp2 softmax + defer-max(8) + cvt_pk pack. Softmax denominator l folded into
// PV via a ones-column B fragment (accumulates in ol, rescaled with oa).
__global__ __launch_bounds__(256, 4) void fattn_k(const unsigned short* __restrict__ qkv,
                                                  unsigned short* __restrict__ ao){
  __shared__ unsigned short Ks[2][64*64];
  __shared__ unsigned short Vt[2][64*64];
  __shared__ unsigned short Ps[64*64];
  const int qt = blockIdx.x, h = blockIdx.y, b = blockIdx.z;
  const int tid = threadIdx.x, w = tid>>6, lane = tid&63;
  const int l15 = lane&15, l4 = lane>>4;
  const size_t rowB = 3072;                 // bytes per token row (1536 bf16)
  const char* base = (const char*)qkv + (size_t)b*SEQ*rowB;
  const char* Kg = base + 1024 + h*128;
  const char* Vg = base + 2048 + h*128;
  const float C2 = 0.18033688f;             // 0.125 * log2(e)

  // Q fragment (B-operand): q = qt*64 + w*16 + l15, hd = ks*32 + l4*8 + e
  bhalf8 qf[2];
  {
    const char* qrow = base + (size_t)(qt*64 + w*16 + l15)*rowB + h*128;
    qf[0] = *(const bhalf8*)(qrow + l4*16);
    qf[1] = *(const bhalf8*)(qrow + l4*16 + 64);
  }
  // ones B-fragment: V_ones[kv][d] = (d==0) ? 1 : 0  -> PV accumulates row sums
  bhalf8 v1;
  {
    short o = (l15==0) ? (short)0x3F80 : (short)0;
    v1 = (bhalf8){o,o,o,o,o,o,o,o};
  }

  const f32x4 z = {0.f,0.f,0.f,0.f};
  f32x4 oa[4], ol = z;
  #pragma unroll
  for (int i=0;i<4;++i) oa[i] = z;
  float mj = -INFINITY;

  // K staging (gll16, pre-swizzled source): wave w stages kv rows w*16..+15
  const int srow  = lane>>3;
  const int sbyte = ((lane&7)*16) ^ (srow<<4);
  // V staging: thread covers column vd = lane; wave w stages kv rows w*16..+15
  const int vd = lane;
  const int vrot = (vd>>3)&3;     // write-order rotation -> spread banks

  unsigned short vload[16];
  // prologue: tile 0
  #pragma unroll
  for (int i=0;i<2;++i){
    int c = w*2 + i, r = c*8 + srow;
    gll16(Kg + (size_t)r*rowB + sbyte, (char*)Ks[0] + c*1024);
  }
  #pragma unroll
  for (int i=0;i<16;++i)
    vload[i] = *(const unsigned short*)(Vg + (size_t)(w*16 + i)*rowB + vd*2);

  int cur = 0;
  for (int kt=0; kt<SEQ/64; ++kt){
    // write Vt[cur] from regs: 4 b64 swizzled writes, rotation-permuted
    #pragma unroll
    for (int i=0;i<4;++i){
      int p = (i + vrot) & 3;
      unsigned lo = (unsigned)vload[p*4+0] | ((unsigned)vload[p*4+1]<<16);
      unsigned hi = (unsigned)vload[p*4+2] | ((unsigned)vload[p*4+3]<<16);
      uint2 pk; pk.x = lo; pk.y = hi;
      int byo = (w*32 + p*8) ^ ((vd&7)<<4);
      *(uint2*)((char*)Vt[cur] + vd*128 + byo) = pk;
    }
    __syncthreads();   // Ks[cur] gll16 drained + Vt[cur] visible

    // prefetch next tile (K via gll16 into other buffer; V into regs)
    if (kt+1 < SEQ/64){
      #pragma unroll
      for (int i=0;i<2;++i){
        int c = w*2 + i, r = c*8 + srow;
        gll16(Kg + (size_t)((kt+1)*64 + r)*rowB + sbyte, (char*)Ks[cur^1] + c*1024);
      }
      #pragma unroll
      for (int i=0;i<16;++i)
        vload[i] = *(const unsigned short*)(Vg + (size_t)((kt+1)*64 + w*16 + i)*rowB + vd*2);
    }

    // ---- compute from buffers [cur] ----
    bhalf8 kf[4][2];
    #pragma unroll
    for (int fc=0; fc<4; ++fc){
      int kr = fc*16 + l15;
      #pragma unroll
      for (int ks=0; ks<2; ++ks){
        int byo = (l4*16 + ks*64) ^ ((kr&7)<<4);
        kf[fc][ks] = *(const bhalf8*)((const char*)Ks[cur] + kr*128 + byo);
      }
    }
    f32x4 s[4];
    #pragma unroll
    for (int i=0;i<4;++i) s[i] = z;
    __builtin_amdgcn_s_setprio(1);
    #pragma unroll
    for (int ks=0; ks<2; ++ks)
      #pragma unroll
      for (int fc=0; fc<4; ++fc)
        s[fc] = __builtin_amdgcn_mfma_f32_16x16x32_bf16(kf[fc][ks], qf[ks], s[fc], 0, 0, 0);
    __builtin_amdgcn_s_setprio(0);

    // online softmax in exp2-space, defer-max THR=8
    {
      float rm0 = fmaxf(fmaxf(s[0][0],s[0][1]), fmaxf(s[0][2],s[0][3]));
      float rm1 = fmaxf(fmaxf(s[1][0],s[1][1]), fmaxf(s[1][2],s[1][3]));
      float rm2 = fmaxf(fmaxf(s[2][0],s[2][1]), fmaxf(s[2][2],s[2][3]));
      float rm3 = fmaxf(fmaxf(s[3][0],s[3][1]), fmaxf(s[3][2],s[3][3]));
      float rm = fmaxf(fmaxf(rm0,rm1), fmaxf(rm2,rm3));
      rm = fmaxf(rm, __shfl_xor(rm,16));
      rm = fmaxf(rm, __shfl_xor(rm,32));
      float tmax = rm * C2;
      if (__any(tmax > mj + 8.f)){
        float mn = fmaxf(mj, tmax);
        float sc = exp2_hw(mj - mn);
        mj = mn;
        float scj0 = __shfl(sc, l4*4+0), scj1 = __shfl(sc, l4*4+1);
        float scj2 = __shfl(sc, l4*4+2), scj3 = __shfl(sc, l4*4+3);
        #pragma unroll
        for (int fc=0; fc<4; ++fc){
          oa[fc][0] *= scj0; oa[fc][1] *= scj1;
          oa[fc][2] *= scj2; oa[fc][3] *= scj3;
        }
        ol[0] *= scj0; ol[1] *= scj1; ol[2] *= scj2; ol[3] *= scj3;
      }
      // P = exp2(C2*s - mj); pack (cvt_pk) -> 4 b64 swizzled writes
      int qrow = w*16 + l15;
      #pragma unroll
      for (int fc=0; fc<4; ++fc){
        float p0 = exp2_hw(fmaf(C2, s[fc][0], -mj));
        float p1 = exp2_hw(fmaf(C2, s[fc][1], -mj));
        float p2 = exp2_hw(fmaf(C2, s[fc][2], -mj));
        float p3 = exp2_hw(fmaf(C2, s[fc][3], -mj));
        unsigned lo, hi;
        asm volatile("v_cvt_pk_bf16_f32 %0, %1, %2" : "=v"(lo) : "v"(p0), "v"(p1));
        asm volatile("v_cvt_pk_bf16_f32 %0, %1, %2" : "=v"(hi) : "v"(p2), "v"(p3));
        uint2 pk; pk.x = lo; pk.y = hi;
        int byo = (fc*32 + l4*8) ^ ((l15&7)<<4);
        *(uint2*)((char*)Ps + qrow*128 + byo) = pk;
      }
    }

    // V fragments (B-operand): lane holds V[kv=ks*32+l4*8+e][d=fc*16+l15]
    bhalf8 vf[4][2];
    #pragma unroll
    for (int fc=0; fc<4; ++fc){
      int d = fc*16 + l15;
      #pragma unroll
      for (int ks=0; ks<2; ++ks){
        int byo = (ks*64 + l4*16) ^ ((d&7)<<4);
        vf[fc][ks] = *(const bhalf8*)((const char*)Vt[cur] + d*128 + byo);
      }
    }
    // O += P V ; ol += P 1 (row sums)
    {
      int qrow = w*16 + l15;
      bhalf8 pf[2];
      #pragma unroll
      for (int ks=0; ks<2; ++ks){
        int byo = (ks*64 + l4*16) ^ ((l15&7)<<4);
        pf[ks] = *(const bhalf8*)((const char*)Ps + qrow*128 + byo);
      }
      __builtin_amdgcn_s_setprio(1);
      #pragma unroll
      for (int ks=0; ks<2; ++ks){
        #pragma unroll
        for (int fc=0; fc<4; ++fc)
          oa[fc] = __builtin_amdgcn_mfma_f32_16x16x32_bf16(pf[ks], vf[fc][ks], oa[fc], 0, 0, 0);
        ol = __builtin_amdgcn_mfma_f32_16x16x32_bf16(pf[ks], v1, ol, 0, 0, 0);
      }
      __builtin_amdgcn_s_setprio(0);
    }
    cur ^= 1;
  }

  // epilogue: row q = l4*4+j sum lives at lane (l4*16), col 0, reg j
  {
    float li[4];
    #pragma unroll
    for (int j=0;j<4;++j) li[j] = 1.f/__shfl(ol[j], l4<<4);
    #pragma unroll
    for (int fc=0; fc<4; ++fc){
      int col = h*64 + fc*16 + l15;
      size_t r0 = (size_t)(b*SEQ + qt*64 + w*16 + l4*4);
      ao[(r0+0)*D_MODEL + col] = f2b(oa[fc][0]*li[0]);
      ao[(r0+1)*D_MODEL + col] = f2b(oa[fc][1]*li[1]);
      ao[(r0+2)*D_MODEL + col] = f2b(oa[fc][2]*li[2]);
      ao[(r0+3)*D_MODEL + col] = f2b(oa[fc][3]*li[3]);
    }
  }
}

// ---------- LayerNorm over D=512; MODE 0: A, 1: A+B, 2: sigmoid(A)*B ----------
template<int MODE, int WF32, int WB16>
__global__ __launch_bounds__(256) void ln_k(const float* A, const float* Bp,
    const float* g, const float* be, float* outf, unsigned short* outb){
  __shared__ float lds[8];
  const size_t off = (size_t)blockIdx.x * D_MODEL;
  const int tid = threadIdx.x;
  float a0 = A[off+tid], a1 = A[off+tid+256];
  if (MODE==1){ a0 += Bp[off+tid]; a1 += Bp[off+tid+256]; }
  if (MODE==2){ a0 = sigmoidf_(a0)*Bp[off+tid]; a1 = sigmoidf_(a1)*Bp[off+tid+256]; }
  float mean = block_sum(a0+a1, lds) * (1.f/512.f);
  float d0=a0-mean, d1=a1-mean;
  float var = block_sum(d0*d0+d1*d1, lds) * (1.f/512.f);
  float rstd = rsqrtf(var + 1e-5f);
  float r0 = d0*rstd*g[tid]     + be[tid];
  float r1 = d1*rstd*g[tid+256] + be[tid+256];
  if (WF32){ outf[off+tid] = r0; outf[off+tid+256] = r1; }
  if (WB16){ outb[off+tid] = f2b(r0); outb[off+tid+256] = f2b(r1); }
}

// ---------- fused: x1 = LN(A+B); then scan prep from x1 ----------
__global__ __launch_bounds__(256) void ln_scan_k(const float* A, const float* Bp,
    const float* __restrict__ g, const float* __restrict__ be, const float* __restrict__ tm,
    float* __restrict__ x1out, float* dec, float* u,
    float* __restrict__ dm, float* __restrict__ es){
  __shared__ float lds[8];
  const size_t row = blockIdx.x;
  const size_t off = row * D_MODEL;
  const int tid = threadIdx.x;
  float a0 = A[off+tid] + Bp[off+tid];
  float a1 = A[off+tid+256] + Bp[off+tid+256];
  float mean = block_sum(a0+a1, lds) * (1.f/512.f);
  float d0=a0-mean, d1=a1-mean;
  float var = block_sum(d0*d0+d1*d1, lds) * (1.f/512.f);
  float rstd = rsqrtf(var + 1e-5f);
  float r0 = d0*rstd*g[tid]     + be[tid];
  float r1 = d1*rstd*g[tid+256] + be[tid+256];
  x1out[off+tid] = r0; x1out[off+tid+256] = r1;
  float dc0 = sigmoidf_(r0*tm[tid]), dc1 = sigmoidf_(r1*tm[tid+256]);
  float e0 = expf(r0), e1 = expf(r1);
  dec[off+tid]=dc0; dec[off+tid+256]=dc1;
  u[off+tid]=e0*r0; u[off+tid+256]=e1*r1;
  float dsum = block_sum(dc0+dc1, lds);
  float esum = block_sum(e0+e1, lds);
  if (tid==0){ dm[row]=dsum*(1.f/512.f); es[row]=esum; }
}

// ---------- fused: coupled = LN(sigmoid(R)*V); x2 = LN(X1 + coupled) ----------
__global__ __launch_bounds__(256) void ln2x_k(const float* R, const float* V, const float* X1,
    const float* __restrict__ g1, const float* __restrict__ b1_,
    const float* __restrict__ g2, const float* __restrict__ b2_,
    float* x2f, unsigned short* __restrict__ x2b){
  __shared__ float lds[8];
  const size_t off = (size_t)blockIdx.x * D_MODEL;
  const int tid = threadIdx.x;
  float a0 = sigmoidf_(R[off+tid])*V[off+tid];
  float a1 = sigmoidf_(R[off+tid+256])*V[off+tid+256];
  float mean = block_sum(a0+a1, lds) * (1.f/512.f);
  float d0=a0-mean, d1=a1-mean;
  float var = block_sum(d0*d0+d1*d1, lds) * (1.f/512.f);
  float rstd = rsqrtf(var + 1e-5f);
  float c0 = d0*rstd*g1[tid]     + b1_[tid];
  float c1 = d1*rstd*g1[tid+256] + b1_[tid+256];
  float t0 = X1[off+tid] + c0, t1 = X1[off+tid+256] + c1;
  float mean2 = block_sum(t0+t1, lds) * (1.f/512.f);
  float e0=t0-mean2, e1=t1-mean2;
  float var2 = block_sum(e0*e0+e1*e1, lds) * (1.f/512.f);
  float rstd2 = rsqrtf(var2 + 1e-5f);
  float r0 = e0*rstd2*g2[tid]     + b2_[tid];
  float r1 = e1*rstd2*g2[tid+256] + b2_[tid+256];
  x2f[off+tid] = r0; x2f[off+tid+256] = r1;
  x2b[off+tid] = f2b(r0); x2b[off+tid+256] = f2b(r1);
}

// ---------- scalar 'a' scan per batch ----------
__global__ __launch_bounds__(256) void ascan_k(const float* __restrict__ dm, const float* __restrict__ es,
                                               float* __restrict__ a_out){
  __shared__ float sG[256], sU[256];
  const int b = blockIdx.x, tid = threadIdx.x;
  const float* dmb = dm + (size_t)b*SEQ;
  const float* esb = es + (size_t)b*SEQ;
  const int t0 = tid*8;
  float gi[8], ui[8];
  #pragma unroll
  for (int i=0;i<8;++i){ gi[i]=dmb[t0+i]; ui[i]=esb[t0+i]; }
  float G=1.f, U=0.f;
  #pragma unroll
  for (int i=0;i<8;++i){ U = gi[i]*U + ui[i]; G *= gi[i]; }
  sG[tid]=G; sU[tid]=U;
  __syncthreads();
  for (int off=1; off<256; off<<=1){
    float pg=1.f, pu=0.f;
    bool act = tid >= off;
    if (act){ pg = sG[tid-off]; pu = sU[tid-off]; }
    __syncthreads();
    if (act){ sU[tid] = sG[tid]*pu + sU[tid]; sG[tid] = sG[tid]*pg; }
    __syncthreads();
  }
  float a = (tid==0) ? 0.f : sU[tid-1];
  #pragma unroll
  for (int i=0;i<8;++i){ a = gi[i]*a + ui[i]; a_out[(size_t)b*SEQ + t0 + i] = a; }
}

// ---------- b scan: chunked ----------
__global__ __launch_bounds__(512) void bscan_p1(const float* __restrict__ decay, const float* __restrict__ u,
    float* __restrict__ Gc, float* __restrict__ Uc){
  const int c = blockIdx.x, b = blockIdx.y, d = threadIdx.x;
  size_t base = ((size_t)b*SEQ + (size_t)c*CHUNK)*D_MODEL + d;
  float G=1.f, U=0.f;
  for (int i=0;i<CHUNK;++i){
    float g  = decay[base + (size_t)i*D_MODEL];
    float uu = u[base + (size_t)i*D_MODEL];
    U = g*U + uu; G = g*G;
  }
  size_t idx = ((size_t)b*NCHUNK + c)*D_MODEL + d;
  Gc[idx]=G; Uc[idx]=U;
}
__global__ __launch_bounds__(512) void bscan_p2(const float* __restrict__ Gc, const float* __restrict__ Uc,
                                                float* __restrict__ binit){
  const int b = blockIdx.x, d = threadIdx.x;
  float cur = 0.f;
  for (int c=0;c<NCHUNK;++c){
    size_t idx = ((size_t)b*NCHUNK + c)*D_MODEL + d;
    binit[idx] = cur;
    cur = Gc[idx]*cur + Uc[idx];
  }
}
// ---------- fused p3 + LN(merged): writes Mb bf16 directly ----------
__global__ __launch_bounds__(512) void p3ln_k(const float* __restrict__ decay, const float* __restrict__ u,
    const float* __restrict__ binit, const float* __restrict__ a,
    const float* __restrict__ g, const float* __restrict__ be,
    unsigned short* __restrict__ mb){
  __shared__ float lds[8];
  const int c = blockIdx.x, b = blockIdx.y, d = threadIdx.x;
  size_t base = ((size_t)b*SEQ + (size_t)c*CHUNK)*D_MODEL + d;
  float bv = binit[((size_t)b*NCHUNK + c)*D_MODEL + d];
  float gg = g[d], bb = be[d];
  for (int i=0;i<CHUNK;++i){
    float gd = decay[base + (size_t)i*D_MODEL];
    float uu = u[base + (size_t)i*D_MODEL];
    bv = gd*bv + uu;
    float av = a[(size_t)b*SEQ + (size_t)c*CHUNK + i];
    float val = bv / (av + 1e-8f);
    float mean = block_sum(val, lds) * (1.f/512.f);
    float dv = val - mean;
    float var = block_sum(dv*dv, lds) * (1.f/512.f);
    float rstd = rsqrtf(var + 1e-5f);
    mb[base + (size_t)i*D_MODEL] = f2b(dv*rstd*gg + bb);
  }
}

extern "C" void kernel_launch(void* const* d_in, const int* in_sizes, int n_in,
                              void* d_out, int out_size, void* d_ws, size_t ws_size,
                              hipStream_t stream){
  const float* x     = (const float*)d_in[0];
  const float* xp    = (const float*)d_in[1];
  const float* mu    = (const float*)d_in[2];
  const float* in_w  = (const float*)d_in[3];
  const float* in_b  = (const float*)d_in[4];
  const float* out_w = (const float*)d_in[5];
  const float* out_b = (const float*)d_in[6];
  const float* ln1_g = (const float*)d_in[7];
  const float* ln1_b = (const float*)d_in[8];
  const float* tm    = (const float*)d_in[9];
  const float* sm_g  = (const float*)d_in[10];
  const float* sm_b  = (const float*)d_in[11];
  const float* wr_w  = (const float*)d_in[12];
  const float* wr_b  = (const float*)d_in[13];
  const float* wv_w  = (const float*)d_in[14];
  const float* wv_b  = (const float*)d_in[15];
  const float* sc_g  = (const float*)d_in[16];
  const float* sc_b  = (const float*)d_in[17];
  const float* ln2_g = (const float*)d_in[18];
  const float* ln2_b = (const float*)d_in[19];
  const float* w1    = (const float*)d_in[20];
  const float* b1    = (const float*)d_in[21];
  const float* w2    = (const float*)d_in[22];
  const float* b2    = (const float*)d_in[23];
  const float* ln3_g = (const float*)d_in[24];
  const float* ln3_b = (const float*)d_in[25];
  float* out = (float*)d_out;
  float* ws  = (float*)d_ws;

  const size_t N = (size_t)M_TOK*D_MODEL;   // 4,194,304
  float* S0f = ws;
  float* S1f = ws + N;
  float* S2f = ws + 2*N;
  float* EX  = ws + 3*N;
  float* dm    = EX;
  float* es    = EX + 8192;
  float* aarr  = EX + 16384;
  float* Gc    = EX + 24576;
  float* Uc    = Gc + 131072;
  float* binit = Uc + 131072;

  unsigned short* SB = (unsigned short*)(ws + 3*N + N/4);
  unsigned short* Wq = SB;
  unsigned short* Wo = Wq + 786432;
  unsigned short* Wr = Wo + 262144;
  unsigned short* Wv = Wr + 262144;
  unsigned short* W1 = Wv + 262144;
  unsigned short* W2 = W1 + 1048576;
  unsigned short* Xb = W2 + 1048576;
  unsigned short* Mb = Xb + N;
  unsigned short* U  = Mb + N;
  unsigned short* Qb  = U;
  unsigned short* AOb = U + 12*1024*1024;
  unsigned short* Hb  = U;

  // 0. all weight converts (one launch)
  cvtall_k<<<3584, 256, 0, stream>>>(in_w, out_w, wr_w, wv_w, w1, w2,
                                     Wq, Wo, Wr, Wv, W1, W2);
  // 1. shifted -> S0f + Xb
  shift2_k<<<4096, 256, 0, stream>>>(x, xp, mu, S0f, Xb, (int)(N/4));
  // 2. qkv -> Qb
  mgemm_k<0,1><<<dim3(12,64), 256, 0, stream>>>(Xb, Wq, in_b, nullptr, Qb, 1536, 512);
  // 3. flash attention -> AOb (QBLK=64, grid 1024, 4 waves)
  fattn_k<<<dim3(SEQ/64, NH, BATCH), 256, 0, stream>>>(Qb, AOb);
  // 4. out-proj -> S1f
  mgemm64_k<0,0><<<dim3(8,64), 256, 0, stream>>>(AOb, Wo, nullptr, out_b, nullptr, S1f, nullptr, 512, 512);
  // 5+6. x1 = LN(shifted+proj) -> S2f; decay -> S0f; u -> S1f; dm/es
  ln_scan_k<<<M_TOK, 256, 0, stream>>>(S0f, S1f, ln1_g, ln1_b, tm, S2f, S0f, S1f, dm, es);
  // 7. 'a' scan
  ascan_k<<<BATCH, 256, 0, stream>>>(dm, es, aarr);
  // 8-9. 'b' scan stages
  bscan_p1<<<dim3(NCHUNK, BATCH), 512, 0, stream>>>(S0f, S1f, Gc, Uc);
  bscan_p2<<<BATCH, 512, 0, stream>>>(Gc, Uc, binit);
  // 10. p3 + LN(merged) fused -> Mb (bf16)
  p3ln_k<<<dim3(NCHUNK, BATCH), 512, 0, stream>>>(S0f, S1f, binit, aarr, sm_g, sm_b, Mb);
  // 11. r -> S0f, v -> S1f (fused single launch)
  mgemm64_k<0,1><<<dim3(16,64), 256, 0, stream>>>(Mb, Wr, Wv, wr_b, wv_b, S0f, S1f, 512, 512);
  // 12+13. coupled = LN(sigmoid(r)*v); x2 = LN(x1+coupled) -> S0f + Xb
  ln2x_k<<<M_TOK, 256, 0, stream>>>(S0f, S1f, S2f, sc_g, sc_b, ln2_g, ln2_b, S0f, Xb);
  // 14. hidden = relu(x2 @ w1.T + b1) -> Hb
  mgemm_k<1,1><<<dim3(16,64), 256, 0, stream>>>(Xb, W1, b1, nullptr, Hb, 2048, 512);
  // 15. ffnout -> S1f
  mgemm64_k<0,0><<<dim3(8,64), 256, 0, stream>>>(Hb, W2, nullptr, b2, nullptr, S1f, nullptr, 512, 2048);
  // 16. out = LN(x2 + ffnout)
  ln_k<1,1,0><<<M_TOK, 256, 0, stream>>>(S0f, S1f, ln3_g, ln3_b, out, nullptr);
}

// Round 9
// 316.058 us; speedup vs baseline: 1.1128x; 1.1128x over previous
//
#include <hip/hip_runtime.h>
#include <math.h>

#define D_MODEL 512
#define SEQ     2048
#define BATCH   4
#define NH      8
#define HD      64
#define CHUNK   32
#define NCHUNK  64
#define M_TOK   (BATCH*SEQ)   // 8192

typedef __attribute__((ext_vector_type(8))) short bhalf8;   // 8 bf16 = 4 VGPR
typedef __attribute__((ext_vector_type(4))) float f32x4;

__device__ __forceinline__ float sigmoidf_(float x){ return 1.f/(1.f+expf(-x)); }

__device__ __forceinline__ unsigned short f2b(float f){   // fp32 -> bf16 RNE
  unsigned u = __float_as_uint(f);
  u += 0x7FFFu + ((u>>16)&1u);
  return (unsigned short)(u>>16);
}

__device__ __forceinline__ void gll16(const void* g, void* l){
  __builtin_amdgcn_global_load_lds(
      (const __attribute__((address_space(1))) unsigned int*)g,
      (__attribute__((address_space(3))) unsigned int*)l, 16, 0, 0);
}

__device__ __forceinline__ float exp2_hw(float x){
  float r;
  asm volatile("v_exp_f32 %0, %1" : "=v"(r) : "v"(x));
  return r;
}

// ---------- block reduction (blockDim up to 512) ----------
__device__ __forceinline__ float block_sum(float v, float* lds){
  #pragma unroll
  for (int o=32;o>0;o>>=1) v += __shfl_xor(v,o);
  int w = threadIdx.x>>6, l = threadIdx.x&63;
  if (l==0) lds[w]=v;
  __syncthreads();
  float t=0.f; int nw = blockDim.x>>6;
  for (int i=0;i<nw;++i) t+=lds[i];
  __syncthreads();
  return t;
}

// ---------- all weight converts in one launch ----------
__global__ void cvtall_k(const float* __restrict__ s0,const float* __restrict__ s1,
                         const float* __restrict__ s2,const float* __restrict__ s3,
                         const float* __restrict__ s4,const float* __restrict__ s5,
                         unsigned short* __restrict__ d0,unsigned short* __restrict__ d1,
                         unsigned short* __restrict__ d2,unsigned short* __restrict__ d3,
                         unsigned short* __restrict__ d4,unsigned short* __restrict__ d5){
  int j = blockIdx.x*blockDim.x + threadIdx.x;
  const float* s; unsigned short* d;
  if (j < 196608){ s=s0; d=d0; }
  else if ((j-=196608) < 65536){ s=s1; d=d1; }
  else if ((j-=65536)  < 65536){ s=s2; d=d2; }
  else if ((j-=65536)  < 65536){ s=s3; d=d3; }
  else if ((j-=65536)  < 262144){ s=s4; d=d4; }
  else if ((j-=262144) < 262144){ s=s5; d=d5; }
  else return;
  float4 v = ((const float4*)s)[j];
  unsigned a=f2b(v.x), b=f2b(v.y), c=f2b(v.z), e=f2b(v.w);
  uint2 p; p.x = a | (b<<16); p.y = c | (e<<16);
  ((uint2*)d)[j] = p;
}

// ---------- shift: fp32 out + bf16 out ----------
__global__ void shift2_k(const float* __restrict__ x, const float* __restrict__ xp,
                         const float* __restrict__ mu, float* __restrict__ of,
                         unsigned short* __restrict__ ob, int n4){
  int i = blockIdx.x*blockDim.x + threadIdx.x;
  if (i < n4){
    float m = mu[0];
    float4 a = ((const float4*)x)[i], p = ((const float4*)xp)[i];
    float4 r;
    r.x = m*a.x + (1.f-m)*p.x; r.y = m*a.y + (1.f-m)*p.y;
    r.z = m*a.z + (1.f-m)*p.z; r.w = m*a.w + (1.f-m)*p.w;
    ((float4*)of)[i] = r;
    unsigned A=f2b(r.x), B=f2b(r.y), C=f2b(r.z), E=f2b(r.w);
    uint2 q; q.x = A | (B<<16); q.y = C | (E<<16);
    ((uint2*)ob)[i] = q;
  }
}

// ---------- bf16 MFMA GEMM 128x128 (verified) ----------
template<int ACT, int OUTB>
__global__ __launch_bounds__(256) void mgemm_k(const unsigned short* __restrict__ A,
    const unsigned short* __restrict__ W, const float* __restrict__ bias,
    float* __restrict__ Yf, unsigned short* __restrict__ Yb, int Nd, int K){
  __shared__ unsigned short As[128*64];
  __shared__ unsigned short Bs[128*64];
  const int tid = threadIdx.x;
  const int w = tid>>6, lane = tid&63;
  const int l15 = lane&15, l4 = lane>>4;
  const int wr = w>>1, wc = w&1;
  const int bn = blockIdx.x, bm = blockIdx.y;

  const size_t Kb = (size_t)K*2;
  const int srow  = lane>>3;
  const int sbyte = ((lane&7)*16) ^ (srow<<4);
  const char* Ag = (const char*)A + (size_t)(bm*128)*Kb + sbyte;
  const char* Wg = (const char*)W + (size_t)(bn*128)*Kb + sbyte;

  f32x4 acc[4][4];
  const f32x4 z = {0.f,0.f,0.f,0.f};
  #pragma unroll
  for (int i=0;i<4;++i)
    #pragma unroll
    for (int j=0;j<4;++j) acc[i][j] = z;

  const int KT = K/64;
  for (int kt=0; kt<KT; ++kt){
    if (kt) __syncthreads();
    const size_t kOff = (size_t)kt*128;
    #pragma unroll
    for (int i=0;i<4;++i){
      int c = w*4 + i;
      int r = c*8 + srow;
      gll16(Ag + (size_t)r*Kb + kOff, (char*)As + c*1024);
      gll16(Wg + (size_t)r*Kb + kOff, (char*)Bs + c*1024);
    }
    __syncthreads();

    bhalf8 af[4][2], bf_[4][2];
    #pragma unroll
    for (int fr=0; fr<4; ++fr){
      int row = wr*64 + fr*16 + l15;
      #pragma unroll
      for (int ks=0; ks<2; ++ks){
        int byo = (l4*16 + ks*64) ^ ((row&7)<<4);
        af[fr][ks] = *(const bhalf8*)((const char*)As + row*128 + byo);
      }
    }
    #pragma unroll
    for (int fc=0; fc<4; ++fc){
      int row = wc*64 + fc*16 + l15;
      #pragma unroll
      for (int ks=0; ks<2; ++ks){
        int byo = (l4*16 + ks*64) ^ ((row&7)<<4);
        bf_[fc][ks] = *(const bhalf8*)((const char*)Bs + row*128 + byo);
      }
    }
    #pragma unroll
    for (int ks=0; ks<2; ++ks)
      #pragma unroll
      for (int fr=0; fr<4; ++fr)
        #pragma unroll
        for (int fc=0; fc<4; ++fc)
          acc[fr][fc] = __builtin_amdgcn_mfma_f32_16x16x32_bf16(af[fr][ks], bf_[fc][ks], acc[fr][fc], 0, 0, 0);
  }

  const int rowBase = bm*128 + wr*64;
  const int colBase = bn*128 + wc*64;
  #pragma unroll
  for (int fc=0; fc<4; ++fc){
    int col = colBase + fc*16 + l15;
    float bv = bias[col];
    #pragma unroll
    for (int fr=0; fr<4; ++fr){
      #pragma unroll
      for (int j=0; j<4; ++j){
        int row = rowBase + fr*16 + l4*4 + j;
        float v = acc[fr][fc][j] + bv;
        if (ACT) v = fmaxf(v, 0.f);
        if (OUTB) Yb[(size_t)row*Nd + col] = f2b(v);
        else      Yf[(size_t)row*Nd + col] = v;
      }
    }
  }
}

// ---------- bf16 MFMA GEMM 128x64 (N=512 shapes) ----------
// FUSE2: blockIdx.x in [0,16): bn>=8 selects {W1v,bias1,Y1}.
template<int ACT, int FUSE2>
__global__ __launch_bounds__(256) void mgemm64_k(const unsigned short* __restrict__ A,
    const unsigned short* __restrict__ W0, const unsigned short* __restrict__ W1v,
    const float* __restrict__ bias0, const float* __restrict__ bias1,
    float* __restrict__ Y0, float* __restrict__ Y1, int Nd, int K){
  __shared__ unsigned short As[128*64];
  __shared__ unsigned short Bs[64*64];
  const int tid = threadIdx.x;
  const int w = tid>>6, lane = tid&63;
  const int l15 = lane&15, l4 = lane>>4;
  const int wr = w>>1, wc = w&1;
  int bn = blockIdx.x;
  const int bm = blockIdx.y;
  const unsigned short* W = W0;
  const float* bias = bias0;
  float* Yf = Y0;
  if (FUSE2 && bn >= 8){ W = W1v; bias = bias1; Yf = Y1; bn -= 8; }

  const size_t Kb = (size_t)K*2;
  const int srow  = lane>>3;
  const int sbyte = ((lane&7)*16) ^ (srow<<4);
  const char* Ag = (const char*)A + (size_t)(bm*128)*Kb + sbyte;
  const char* Wg = (const char*)W + (size_t)(bn*64)*Kb + sbyte;

  f32x4 acc[4][2];
  const f32x4 z = {0.f,0.f,0.f,0.f};
  #pragma unroll
  for (int i=0;i<4;++i)
    #pragma unroll
    for (int j=0;j<2;++j) acc[i][j] = z;

  const int KT = K/64;
  for (int kt=0; kt<KT; ++kt){
    if (kt) __syncthreads();
    const size_t kOff = (size_t)kt*128;
    #pragma unroll
    for (int i=0;i<4;++i){
      int c = w*4 + i;
      int r = c*8 + srow;
      gll16(Ag + (size_t)r*Kb + kOff, (char*)As + c*1024);
    }
    #pragma unroll
    for (int i=0;i<2;++i){
      int c = w*2 + i;
      int r = c*8 + srow;
      gll16(Wg + (size_t)r*Kb + kOff, (char*)Bs + c*1024);
    }
    __syncthreads();

    bhalf8 af[4][2], bf_[2][2];
    #pragma unroll
    for (int fr=0; fr<4; ++fr){
      int row = wr*64 + fr*16 + l15;
      #pragma unroll
      for (int ks=0; ks<2; ++ks){
        int byo = (l4*16 + ks*64) ^ ((row&7)<<4);
        af[fr][ks] = *(const bhalf8*)((const char*)As + row*128 + byo);
      }
    }
    #pragma unroll
    for (int fc=0; fc<2; ++fc){
      int row = wc*32 + fc*16 + l15;
      #pragma unroll
      for (int ks=0; ks<2; ++ks){
        int byo = (l4*16 + ks*64) ^ ((row&7)<<4);
        bf_[fc][ks] = *(const bhalf8*)((const char*)Bs + row*128 + byo);
      }
    }
    #pragma unroll
    for (int ks=0; ks<2; ++ks)
      #pragma unroll
      for (int fr=0; fr<4; ++fr)
        #pragma unroll
        for (int fc=0; fc<2; ++fc)
          acc[fr][fc] = __builtin_amdgcn_mfma_f32_16x16x32_bf16(af[fr][ks], bf_[fc][ks], acc[fr][fc], 0, 0, 0);
  }

  const int rowBase = bm*128 + wr*64;
  const int colBase = bn*64 + wc*32;
  #pragma unroll
  for (int fc=0; fc<2; ++fc){
    int col = colBase + fc*16 + l15;
    float bv = bias[col];
    #pragma unroll
    for (int fr=0; fr<4; ++fr){
      #pragma unroll
      for (int j=0; j<4; ++j){
        int row = rowBase + fr*16 + l4*4 + j;
        float v = acc[fr][fc][j] + bv;
        if (ACT) v = fmaxf(v, 0.f);
        Yf[(size_t)row*Nd + col] = v;
      }
    }
  }
}

// ---------- bf16 MFMA flash attention: QBLK=128, 8 waves (R7 structure) ----------
// block = (qt, h, b); wave w owns q rows qt*128 + w*16 + [0,16).
// Swapped QK: S^T via mfma(K,Q) -> lane holds S[kv=fc*16+l4*4+j][q=l15].
// exp2 softmax + defer-max(8) + cvt_pk pack + ones-column l-in-MFMA (R8 keep).
__global__ __launch_bounds__(512, 4) void fattn_k(const unsigned short* __restrict__ qkv,
                                                  unsigned short* __restrict__ ao){
  __shared__ unsigned short Ks[2][64*64];
  __shared__ unsigned short Vt[2][64*64];
  __shared__ unsigned short Ps[128*64];
  const int qt = blockIdx.x, h = blockIdx.y, b = blockIdx.z;
  const int tid = threadIdx.x, w = tid>>6, lane = tid&63;
  const int l15 = lane&15, l4 = lane>>4;
  const size_t rowB = 3072;                 // bytes per token row (1536 bf16)
  const char* base = (const char*)qkv + (size_t)b*SEQ*rowB;
  const char* Kg = base + 1024 + h*128;
  const char* Vg = base + 2048 + h*128;
  const float C2 = 0.18033688f;             // 0.125 * log2(e)

  // Q fragment (B-operand): q = qt*128 + w*16 + l15, hd = ks*32 + l4*8 + e
  bhalf8 qf[2];
  {
    const char* qrow = base + (size_t)(qt*128 + w*16 + l15)*rowB + h*128;
    qf[0] = *(const bhalf8*)(qrow + l4*16);
    qf[1] = *(const bhalf8*)(qrow + l4*16 + 64);
  }
  // ones B-fragment: V_ones[kv][d] = (d==0) ? 1 : 0  -> PV accumulates row sums
  bhalf8 v1;
  {
    short o = (l15==0) ? (short)0x3F80 : (short)0;
    v1 = (bhalf8){o,o,o,o,o,o,o,o};
  }

  const f32x4 z = {0.f,0.f,0.f,0.f};
  f32x4 oa[4], ol = z;
  #pragma unroll
  for (int i=0;i<4;++i) oa[i] = z;
  float mj = -INFINITY;

  // K staging (gll16, pre-swizzled source): wave w stages kv rows w*8..+7
  const int srow  = lane>>3;
  const int sbyte = ((lane&7)*16) ^ (srow<<4);
  // V staging: thread covers column vd = lane; wave w stages kv rows w*8..+7
  const int vd = lane;
  const int vsel = (vd>>3)&1;     // write-order permute -> fewer bank conflicts

  unsigned short vload[8];
  // prologue: tile 0
  {
    int r = w*8 + srow;
    gll16(Kg + (size_t)r*rowB + sbyte, (char*)Ks[0] + w*1024);
  }
  #pragma unroll
  for (int i=0;i<8;++i)
    vload[i] = *(const unsigned short*)(Vg + (size_t)(w*8 + i)*rowB + vd*2);

  int cur = 0;
  for (int kt=0; kt<SEQ/64; ++kt){
    // write Vt[cur] from regs: 2 b64 swizzled writes, order permuted by vsel
    #pragma unroll
    for (int i=0;i<2;++i){
      int p = i ^ vsel;
      unsigned lo = (unsigned)vload[p*4+0] | ((unsigned)vload[p*4+1]<<16);
      unsigned hi = (unsigned)vload[p*4+2] | ((unsigned)vload[p*4+3]<<16);
      uint2 pk; pk.x = lo; pk.y = hi;
      int byo = (w*16 + p*8) ^ ((vd&7)<<4);
      *(uint2*)((char*)Vt[cur] + vd*128 + byo) = pk;
    }
    __syncthreads();   // Ks[cur] gll16 drained + Vt[cur] visible

    // prefetch next tile (K via gll16 into other buffer; V into regs)
    if (kt+1 < SEQ/64){
      int r = w*8 + srow;
      gll16(Kg + (size_t)((kt+1)*64 + r)*rowB + sbyte, (char*)Ks[cur^1] + w*1024);
      #pragma unroll
      for (int i=0;i<8;++i)
        vload[i] = *(const unsigned short*)(Vg + (size_t)((kt+1)*64 + w*8 + i)*rowB + vd*2);
    }

    // ---- compute from buffers [cur] ----
    bhalf8 kf[4][2];
    #pragma unroll
    for (int fc=0; fc<4; ++fc){
      int kr = fc*16 + l15;
      #pragma unroll
      for (int ks=0; ks<2; ++ks){
        int byo = (l4*16 + ks*64) ^ ((kr&7)<<4);
        kf[fc][ks] = *(const bhalf8*)((const char*)Ks[cur] + kr*128 + byo);
      }
    }
    f32x4 s[4];
    #pragma unroll
    for (int i=0;i<4;++i) s[i] = z;
    __builtin_amdgcn_s_setprio(1);
    #pragma unroll
    for (int ks=0; ks<2; ++ks)
      #pragma unroll
      for (int fc=0; fc<4; ++fc)
        s[fc] = __builtin_amdgcn_mfma_f32_16x16x32_bf16(kf[fc][ks], qf[ks], s[fc], 0, 0, 0);
    __builtin_amdgcn_s_setprio(0);

    // online softmax in exp2-space, defer-max THR=8
    {
      float rm0 = fmaxf(fmaxf(s[0][0],s[0][1]), fmaxf(s[0][2],s[0][3]));
      float rm1 = fmaxf(fmaxf(s[1][0],s[1][1]), fmaxf(s[1][2],s[1][3]));
      float rm2 = fmaxf(fmaxf(s[2][0],s[2][1]), fmaxf(s[2][2],s[2][3]));
      float rm3 = fmaxf(fmaxf(s[3][0],s[3][1]), fmaxf(s[3][2],s[3][3]));
      float rm = fmaxf(fmaxf(rm0,rm1), fmaxf(rm2,rm3));
      rm = fmaxf(rm, __shfl_xor(rm,16));
      rm = fmaxf(rm, __shfl_xor(rm,32));
      float tmax = rm * C2;
      if (__any(tmax > mj + 8.f)){
        float mn = fmaxf(mj, tmax);
        float sc = exp2_hw(mj - mn);
        mj = mn;
        float scj0 = __shfl(sc, l4*4+0), scj1 = __shfl(sc, l4*4+1);
        float scj2 = __shfl(sc, l4*4+2), scj3 = __shfl(sc, l4*4+3);
        #pragma unroll
        for (int fc=0; fc<4; ++fc){
          oa[fc][0] *= scj0; oa[fc][1] *= scj1;
          oa[fc][2] *= scj2; oa[fc][3] *= scj3;
        }
        ol[0] *= scj0; ol[1] *= scj1; ol[2] *= scj2; ol[3] *= scj3;
      }
      // P = exp2(C2*s - mj); pack (cvt_pk) -> 4 b64 swizzled writes
      int qrow = w*16 + l15;
      #pragma unroll
      for (int fc=0; fc<4; ++fc){
        float p0 = exp2_hw(fmaf(C2, s[fc][0], -mj));
        float p1 = exp2_hw(fmaf(C2, s[fc][1], -mj));
        float p2 = exp2_hw(fmaf(C2, s[fc][2], -mj));
        float p3 = exp2_hw(fmaf(C2, s[fc][3], -mj));
        unsigned lo, hi;
        asm volatile("v_cvt_pk_bf16_f32 %0, %1, %2" : "=v"(lo) : "v"(p0), "v"(p1));
        asm volatile("v_cvt_pk_bf16_f32 %0, %1, %2" : "=v"(hi) : "v"(p2), "v"(p3));
        uint2 pk; pk.x = lo; pk.y = hi;
        int byo = (fc*32 + l4*8) ^ ((l15&7)<<4);
        *(uint2*)((char*)Ps + qrow*128 + byo) = pk;
      }
    }

    // V fragments (B-operand): lane holds V[kv=ks*32+l4*8+e][d=fc*16+l15]
    bhalf8 vf[4][2];
    #pragma unroll
    for (int fc=0; fc<4; ++fc){
      int d = fc*16 + l15;
      #pragma unroll
      for (int ks=0; ks<2; ++ks){
        int byo = (ks*64 + l4*16) ^ ((d&7)<<4);
        vf[fc][ks] = *(const bhalf8*)((const char*)Vt[cur] + d*128 + byo);
      }
    }
    // O += P V ; ol += P 1 (row sums)
    {
      int qrow = w*16 + l15;
      bhalf8 pf[2];
      #pragma unroll
      for (int ks=0; ks<2; ++ks){
        int byo = (ks*64 + l4*16) ^ ((l15&7)<<4);
        pf[ks] = *(const bhalf8*)((const char*)Ps + qrow*128 + byo);
      }
      __builtin_amdgcn_s_setprio(1);
      #pragma unroll
      for (int ks=0; ks<2; ++ks){
        #pragma unroll
        for (int fc=0; fc<4; ++fc)
          oa[fc] = __builtin_amdgcn_mfma_f32_16x16x32_bf16(pf[ks], vf[fc][ks], oa[fc], 0, 0, 0);
        ol = __builtin_amdgcn_mfma_f32_16x16x32_bf16(pf[ks], v1, ol, 0, 0, 0);
      }
      __builtin_amdgcn_s_setprio(0);
    }
    cur ^= 1;
  }

  // epilogue: row q = l4*4+j sum lives at lane (l4*16), col 0, reg j
  {
    float li[4];
    #pragma unroll
    for (int j=0;j<4;++j) li[j] = 1.f/__shfl(ol[j], l4<<4);
    #pragma unroll
    for (int fc=0; fc<4; ++fc){
      int col = h*64 + fc*16 + l15;
      size_t r0 = (size_t)(b*SEQ + qt*128 + w*16 + l4*4);
      ao[(r0+0)*D_MODEL + col] = f2b(oa[fc][0]*li[0]);
      ao[(r0+1)*D_MODEL + col] = f2b(oa[fc][1]*li[1]);
      ao[(r0+2)*D_MODEL + col] = f2b(oa[fc][2]*li[2]);
      ao[(r0+3)*D_MODEL + col] = f2b(oa[fc][3]*li[3]);
    }
  }
}

// ---------- LayerNorm over D=512; MODE 0: A, 1: A+B, 2: sigmoid(A)*B ----------
template<int MODE, int WF32, int WB16>
__global__ __launch_bounds__(256) void ln_k(const float* A, const float* Bp,
    const float* g, const float* be, float* outf, unsigned short* outb){
  __shared__ float lds[8];
  const size_t off = (size_t)blockIdx.x * D_MODEL;
  const int tid = threadIdx.x;
  float a0 = A[off+tid], a1 = A[off+tid+256];
  if (MODE==1){ a0 += Bp[off+tid]; a1 += Bp[off+tid+256]; }
  if (MODE==2){ a0 = sigmoidf_(a0)*Bp[off+tid]; a1 = sigmoidf_(a1)*Bp[off+tid+256]; }
  float mean = block_sum(a0+a1, lds) * (1.f/512.f);
  float d0=a0-mean, d1=a1-mean;
  float var = block_sum(d0*d0+d1*d1, lds) * (1.f/512.f);
  float rstd = rsqrtf(var + 1e-5f);
  float r0 = d0*rstd*g[tid]     + be[tid];
  float r1 = d1*rstd*g[tid+256] + be[tid+256];
  if (WF32){ outf[off+tid] = r0; outf[off+tid+256] = r1; }
  if (WB16){ outb[off+tid] = f2b(r0); outb[off+tid+256] = f2b(r1); }
}

// ---------- fused: x1 = LN(A+B); then scan prep from x1 ----------
__global__ __launch_bounds__(256) void ln_scan_k(const float* A, const float* Bp,
    const float* __restrict__ g, const float* __restrict__ be, const float* __restrict__ tm,
    float* __restrict__ x1out, float* dec, float* u,
    float* __restrict__ dm, float* __restrict__ es){
  __shared__ float lds[8];
  const size_t row = blockIdx.x;
  const size_t off = row * D_MODEL;
  const int tid = threadIdx.x;
  float a0 = A[off+tid] + Bp[off+tid];
  float a1 = A[off+tid+256] + Bp[off+tid+256];
  float mean = block_sum(a0+a1, lds) * (1.f/512.f);
  float d0=a0-mean, d1=a1-mean;
  float var = block_sum(d0*d0+d1*d1, lds) * (1.f/512.f);
  float rstd = rsqrtf(var + 1e-5f);
  float r0 = d0*rstd*g[tid]     + be[tid];
  float r1 = d1*rstd*g[tid+256] + be[tid+256];
  x1out[off+tid] = r0; x1out[off+tid+256] = r1;
  float dc0 = sigmoidf_(r0*tm[tid]), dc1 = sigmoidf_(r1*tm[tid+256]);
  float e0 = expf(r0), e1 = expf(r1);
  dec[off+tid]=dc0; dec[off+tid+256]=dc1;
  u[off+tid]=e0*r0; u[off+tid+256]=e1*r1;
  float dsum = block_sum(dc0+dc1, lds);
  float esum = block_sum(e0+e1, lds);
  if (tid==0){ dm[row]=dsum*(1.f/512.f); es[row]=esum; }
}

// ---------- fused: coupled = LN(sigmoid(R)*V); x2 = LN(X1 + coupled) ----------
__global__ __launch_bounds__(256) void ln2x_k(const float* R, const float* V, const float* X1,
    const float* __restrict__ g1, const float* __restrict__ b1_,
    const float* __restrict__ g2, const float* __restrict__ b2_,
    float* x2f, unsigned short* __restrict__ x2b){
  __shared__ float lds[8];
  const size_t off = (size_t)blockIdx.x * D_MODEL;
  const int tid = threadIdx.x;
  float a0 = sigmoidf_(R[off+tid])*V[off+tid];
  float a1 = sigmoidf_(R[off+tid+256])*V[off+tid+256];
  float mean = block_sum(a0+a1, lds) * (1.f/512.f);
  float d0=a0-mean, d1=a1-mean;
  float var = block_sum(d0*d0+d1*d1, lds) * (1.f/512.f);
  float rstd = rsqrtf(var + 1e-5f);
  float c0 = d0*rstd*g1[tid]     + b1_[tid];
  float c1 = d1*rstd*g1[tid+256] + b1_[tid+256];
  float t0 = X1[off+tid] + c0, t1 = X1[off+tid+256] + c1;
  float mean2 = block_sum(t0+t1, lds) * (1.f/512.f);
  float e0=t0-mean2, e1=t1-mean2;
  float var2 = block_sum(e0*e0+e1*e1, lds) * (1.f/512.f);
  float rstd2 = rsqrtf(var2 + 1e-5f);
  float r0 = e0*rstd2*g2[tid]     + b2_[tid];
  float r1 = e1*rstd2*g2[tid+256] + b2_[tid+256];
  x2f[off+tid] = r0; x2f[off+tid+256] = r1;
  x2b[off+tid] = f2b(r0); x2b[off+tid+256] = f2b(r1);
}

// ---------- scalar 'a' scan per batch ----------
__global__ __launch_bounds__(256) void ascan_k(const float* __restrict__ dm, const float* __restrict__ es,
                                               float* __restrict__ a_out){
  __shared__ float sG[256], sU[256];
  const int b = blockIdx.x, tid = threadIdx.x;
  const float* dmb = dm + (size_t)b*SEQ;
  const float* esb = es + (size_t)b*SEQ;
  const int t0 = tid*8;
  float gi[8], ui[8];
  #pragma unroll
  for (int i=0;i<8;++i){ gi[i]=dmb[t0+i]; ui[i]=esb[t0+i]; }
  float G=1.f, U=0.f;
  #pragma unroll
  for (int i=0;i<8;++i){ U = gi[i]*U + ui[i]; G *= gi[i]; }
  sG[tid]=G; sU[tid]=U;
  __syncthreads();
  for (int off=1; off<256; off<<=1){
    float pg=1.f, pu=0.f;
    bool act = tid >= off;
    if (act){ pg = sG[tid-off]; pu = sU[tid-off]; }
    __syncthreads();
    if (act){ sU[tid] = sG[tid]*pu + sU[tid]; sG[tid] = sG[tid]*pg; }
    __syncthreads();
  }
  float a = (tid==0) ? 0.f : sU[tid-1];
  #pragma unroll
  for (int i=0;i<8;++i){ a = gi[i]*a + ui[i]; a_out[(size_t)b*SEQ + t0 + i] = a; }
}

// ---------- b scan: chunked ----------
__global__ __launch_bounds__(512) void bscan_p1(const float* __restrict__ decay, const float* __restrict__ u,
    float* __restrict__ Gc, float* __restrict__ Uc){
  const int c = blockIdx.x, b = blockIdx.y, d = threadIdx.x;
  size_t base = ((size_t)b*SEQ + (size_t)c*CHUNK)*D_MODEL + d;
  float G=1.f, U=0.f;
  for (int i=0;i<CHUNK;++i){
    float g  = decay[base + (size_t)i*D_MODEL];
    float uu = u[base + (size_t)i*D_MODEL];
    U = g*U + uu; G = g*G;
  }
  size_t idx = ((size_t)b*NCHUNK + c)*D_MODEL + d;
  Gc[idx]=G; Uc[idx]=U;
}
__global__ __launch_bounds__(512) void bscan_p2(const float* __restrict__ Gc, const float* __restrict__ Uc,
                                                float* __restrict__ binit){
  const int b = blockIdx.x, d = threadIdx.x;
  float cur = 0.f;
  for (int c=0;c<NCHUNK;++c){
    size_t idx = ((size_t)b*NCHUNK + c)*D_MODEL + d;
    binit[idx] = cur;
    cur = Gc[idx]*cur + Uc[idx];
  }
}
// ---------- fused p3 + LN(merged): writes Mb bf16 directly ----------
__global__ __launch_bounds__(512) void p3ln_k(const float* __restrict__ decay, const float* __restrict__ u,
    const float* __restrict__ binit, const float* __restrict__ a,
    const float* __restrict__ g, const float* __restrict__ be,
    unsigned short* __restrict__ mb){
  __shared__ float lds[8];
  const int c = blockIdx.x, b = blockIdx.y, d = threadIdx.x;
  size_t base = ((size_t)b*SEQ + (size_t)c*CHUNK)*D_MODEL + d;
  float bv = binit[((size_t)b*NCHUNK + c)*D_MODEL + d];
  float gg = g[d], bb = be[d];
  for (int i=0;i<CHUNK;++i){
    float gd = decay[base + (size_t)i*D_MODEL];
    float uu = u[base + (size_t)i*D_MODEL];
    bv = gd*bv + uu;
    float av = a[(size_t)b*SEQ + (size_t)c*CHUNK + i];
    float val = bv / (av + 1e-8f);
    float mean = block_sum(val, lds) * (1.f/512.f);
    float dv = val - mean;
    float var = block_sum(dv*dv, lds) * (1.f/512.f);
    float rstd = rsqrtf(var + 1e-5f);
    mb[base + (size_t)i*D_MODEL] = f2b(dv*rstd*gg + bb);
  }
}

extern "C" void kernel_launch(void* const* d_in, const int* in_sizes, int n_in,
                              void* d_out, int out_size, void* d_ws, size_t ws_size,
                              hipStream_t stream){
  const float* x     = (const float*)d_in[0];
  const float* xp    = (const float*)d_in[1];
  const float* mu    = (const float*)d_in[2];
  const float* in_w  = (const float*)d_in[3];
  const float* in_b  = (const float*)d_in[4];
  const float* out_w = (const float*)d_in[5];
  const float* out_b = (const float*)d_in[6];
  const float* ln1_g = (const float*)d_in[7];
  const float* ln1_b = (const float*)d_in[8];
  const float* tm    = (const float*)d_in[9];
  const float* sm_g  = (const float*)d_in[10];
  const float* sm_b  = (const float*)d_in[11];
  const float* wr_w  = (const float*)d_in[12];
  const float* wr_b  = (const float*)d_in[13];
  const float* wv_w  = (const float*)d_in[14];
  const float* wv_b  = (const float*)d_in[15];
  const float* sc_g  = (const float*)d_in[16];
  const float* sc_b  = (const float*)d_in[17];
  const float* ln2_g = (const float*)d_in[18];
  const float* ln2_b = (const float*)d_in[19];
  const float* w1    = (const float*)d_in[20];
  const float* b1    = (const float*)d_in[21];
  const float* w2    = (const float*)d_in[22];
  const float* b2    = (const float*)d_in[23];
  const float* ln3_g = (const float*)d_in[24];
  const float* ln3_b = (const float*)d_in[25];
  float* out = (float*)d_out;
  float* ws  = (float*)d_ws;

  const size_t N = (size_t)M_TOK*D_MODEL;   // 4,194,304
  float* S0f = ws;
  float* S1f = ws + N;
  float* S2f = ws + 2*N;
  float* EX  = ws + 3*N;
  float* dm    = EX;
  float* es    = EX + 8192;
  float* aarr  = EX + 16384;
  float* Gc    = EX + 24576;
  float* Uc    = Gc + 131072;
  float* binit = Uc + 131072;

  unsigned short* SB = (unsigned short*)(ws + 3*N + N/4);
  unsigned short* Wq = SB;
  unsigned short* Wo = Wq + 786432;
  unsigned short* Wr = Wo + 262144;
  unsigned short* Wv = Wr + 262144;
  unsigned short* W1 = Wv + 262144;
  unsigned short* W2 = W1 + 1048576;
  unsigned short* Xb = W2 + 1048576;
  unsigned short* Mb = Xb + N;
  unsigned short* U  = Mb + N;
  unsigned short* Qb  = U;
  unsigned short* AOb = U + 12*1024*1024;
  unsigned short* Hb  = U;

  // 0. all weight converts (one launch)
  cvtall_k<<<3584, 256, 0, stream>>>(in_w, out_w, wr_w, wv_w, w1, w2,
                                     Wq, Wo, Wr, Wv, W1, W2);
  // 1. shifted -> S0f + Xb
  shift2_k<<<4096, 256, 0, stream>>>(x, xp, mu, S0f, Xb, (int)(N/4));
  // 2. qkv -> Qb
  mgemm_k<0,1><<<dim3(12,64), 256, 0, stream>>>(Xb, Wq, in_b, nullptr, Qb, 1536, 512);
  // 3. flash attention -> AOb (QBLK=128, 512 blocks, 8 waves)
  fattn_k<<<dim3(SEQ/128, NH, BATCH), 512, 0, stream>>>(Qb, AOb);
  // 4. out-proj -> S1f
  mgemm64_k<0,0><<<dim3(8,64), 256, 0, stream>>>(AOb, Wo, nullptr, out_b, nullptr, S1f, nullptr, 512, 512);
  // 5+6. x1 = LN(shifted+proj) -> S2f; decay -> S0f; u -> S1f; dm/es
  ln_scan_k<<<M_TOK, 256, 0, stream>>>(S0f, S1f, ln1_g, ln1_b, tm, S2f, S0f, S1f, dm, es);
  // 7. 'a' scan
  ascan_k<<<BATCH, 256, 0, stream>>>(dm, es, aarr);
  // 8-9. 'b' scan stages
  bscan_p1<<<dim3(NCHUNK, BATCH), 512, 0, stream>>>(S0f, S1f, Gc, Uc);
  bscan_p2<<<BATCH, 512, 0, stream>>>(Gc, Uc, binit);
  // 10. p3 + LN(merged) fused -> Mb (bf16)
  p3ln_k<<<dim3(NCHUNK, BATCH), 512, 0, stream>>>(S0f, S1f, binit, aarr, sm_g, sm_b, Mb);
  // 11. r -> S0f, v -> S1f (fused single launch)
  mgemm64_k<0,1><<<dim3(16,64), 256, 0, stream>>>(Mb, Wr, Wv, wr_b, wv_b, S0f, S1f, 512, 512);
  // 12+13. coupled = LN(sigmoid(r)*v); x2 = LN(x1+coupled) -> S0f + Xb
  ln2x_k<<<M_TOK, 256, 0, stream>>>(S0f, S1f, S2f, sc_g, sc_b, ln2_g, ln2_b, S0f, Xb);
  // 14. hidden = relu(x2 @ w1.T + b1) -> Hb
  mgemm_k<1,1><<<dim3(16,64), 256, 0, stream>>>(Xb, W1, b1, nullptr, Hb, 2048, 512);
  // 15. ffnout -> S1f
  mgemm64_k<0,0><<<dim3(8,64), 256, 0, stream>>>(Hb, W2, nullptr, b2, nullptr, S1f, nullptr, 512, 2048);
  // 16. out = LN(x2 + ffnout)
  ln_k<1,1,0><<<M_TOK, 256, 0, stream>>>(S0f, S1f, ln3_g, ln3_b, out, nullptr);
}

// Round 10
// 262.009 us; speedup vs baseline: 1.3423x; 1.2063x over previous
//
#include <hip/hip_runtime.h>
#include <math.h>

#define D_MODEL 512
#define SEQ     2048
#define BATCH   4
#define NH      8
#define HD      64
#define CHUNK   32
#define NCHUNK  64
#define M_TOK   (BATCH*SEQ)   // 8192

typedef __attribute__((ext_vector_type(8))) short bhalf8;   // 8 bf16 = 4 VGPR
typedef __attribute__((ext_vector_type(4))) float f32x4;

__device__ __forceinline__ float sigmoidf_(float x){ return 1.f/(1.f+expf(-x)); }

__device__ __forceinline__ unsigned short f2b(float f){   // fp32 -> bf16 RNE
  unsigned u = __float_as_uint(f);
  u += 0x7FFFu + ((u>>16)&1u);
  return (unsigned short)(u>>16);
}
__device__ __forceinline__ float b2f(unsigned short h){
  return __uint_as_float(((unsigned)h)<<16);
}

__device__ __forceinline__ void gll16(const void* g, void* l){
  __builtin_amdgcn_global_load_lds(
      (const __attribute__((address_space(1))) unsigned int*)g,
      (__attribute__((address_space(3))) unsigned int*)l, 16, 0, 0);
}

__device__ __forceinline__ float exp2_hw(float x){
  float r;
  asm volatile("v_exp_f32 %0, %1" : "=v"(r) : "v"(x));
  return r;
}

// ---------- paired block reduction: one barrier round for two sums ----------
__device__ __forceinline__ void block_sum2(float& a, float& b, float* lds){
  #pragma unroll
  for (int o=32;o>0;o>>=1){ a += __shfl_xor(a,o); b += __shfl_xor(b,o); }
  int w = threadIdx.x>>6, l = threadIdx.x&63;
  if (l==0){ lds[2*w]=a; lds[2*w+1]=b; }
  __syncthreads();
  float ta=0.f, tb=0.f; int nw = blockDim.x>>6;
  for (int i=0;i<nw;++i){ ta+=lds[2*i]; tb+=lds[2*i+1]; }
  a=ta; b=tb;
  __syncthreads();
}

// ---------- merged: weight converts + shift (one launch) ----------
__global__ void cvtshift_k(const float* __restrict__ s0,const float* __restrict__ s1,
                           const float* __restrict__ s2,const float* __restrict__ s3,
                           const float* __restrict__ s4,const float* __restrict__ s5,
                           unsigned short* __restrict__ d0,unsigned short* __restrict__ d1,
                           unsigned short* __restrict__ d2,unsigned short* __restrict__ d3,
                           unsigned short* __restrict__ d4,unsigned short* __restrict__ d5,
                           const float* __restrict__ x, const float* __restrict__ xp,
                           const float* __restrict__ mu, float* __restrict__ of,
                           unsigned short* __restrict__ ob){
  int t = blockIdx.x*blockDim.x + threadIdx.x;
  if (t < 917504){
    int j = t;
    const float* s; unsigned short* d;
    if (j < 196608){ s=s0; d=d0; }
    else if ((j-=196608) < 65536){ s=s1; d=d1; }
    else if ((j-=65536)  < 65536){ s=s2; d=d2; }
    else if ((j-=65536)  < 65536){ s=s3; d=d3; }
    else if ((j-=65536)  < 262144){ s=s4; d=d4; }
    else { j-=262144; s=s5; d=d5; }
    float4 v = ((const float4*)s)[j];
    unsigned a=f2b(v.x), b=f2b(v.y), c=f2b(v.z), e=f2b(v.w);
    uint2 p; p.x = a | (b<<16); p.y = c | (e<<16);
    ((uint2*)d)[j] = p;
  } else {
    int i = t - 917504;   // 0 .. 1048575
    float m = mu[0];
    float4 a = ((const float4*)x)[i], p = ((const float4*)xp)[i];
    float4 r;
    r.x = m*a.x + (1.f-m)*p.x; r.y = m*a.y + (1.f-m)*p.y;
    r.z = m*a.z + (1.f-m)*p.z; r.w = m*a.w + (1.f-m)*p.w;
    ((float4*)of)[i] = r;
    unsigned A=f2b(r.x), B=f2b(r.y), C=f2b(r.z), E=f2b(r.w);
    uint2 q; q.x = A | (B<<16); q.y = C | (E<<16);
    ((uint2*)ob)[i] = q;
  }
}

// ---------- bf16 MFMA GEMM 128x128, XCD-swizzled ----------
template<int ACT, int OUTB>
__global__ __launch_bounds__(256) void mgemm_k(const unsigned short* __restrict__ A,
    const unsigned short* __restrict__ W, const float* __restrict__ bias,
    float* __restrict__ Yf, unsigned short* __restrict__ Yb, int Nd, int K){
  __shared__ unsigned short As[128*64];
  __shared__ unsigned short Bs[128*64];
  const int tid = threadIdx.x;
  const int w = tid>>6, lane = tid&63;
  const int l15 = lane&15, l4 = lane>>4;
  const int wr = w>>1, wc = w&1;
  const int nwg = gridDim.x*gridDim.y;
  const int orig = blockIdx.y*gridDim.x + blockIdx.x;
  const int swz = (orig&7)*(nwg>>3) + (orig>>3);
  const int bn = swz % gridDim.x;
  const int bm = swz / gridDim.x;

  const size_t Kb = (size_t)K*2;
  const int srow  = lane>>3;
  const int sbyte = ((lane&7)*16) ^ (srow<<4);
  const char* Ag = (const char*)A + (size_t)(bm*128)*Kb + sbyte;
  const char* Wg = (const char*)W + (size_t)(bn*128)*Kb + sbyte;

  f32x4 acc[4][4];
  const f32x4 z = {0.f,0.f,0.f,0.f};
  #pragma unroll
  for (int i=0;i<4;++i)
    #pragma unroll
    for (int j=0;j<4;++j) acc[i][j] = z;

  const int KT = K/64;
  for (int kt=0; kt<KT; ++kt){
    if (kt) __syncthreads();
    const size_t kOff = (size_t)kt*128;
    #pragma unroll
    for (int i=0;i<4;++i){
      int c = w*4 + i;
      int r = c*8 + srow;
      gll16(Ag + (size_t)r*Kb + kOff, (char*)As + c*1024);
      gll16(Wg + (size_t)r*Kb + kOff, (char*)Bs + c*1024);
    }
    __syncthreads();

    bhalf8 af[4][2], bf_[4][2];
    #pragma unroll
    for (int fr=0; fr<4; ++fr){
      int row = wr*64 + fr*16 + l15;
      #pragma unroll
      for (int ks=0; ks<2; ++ks){
        int byo = (l4*16 + ks*64) ^ ((row&7)<<4);
        af[fr][ks] = *(const bhalf8*)((const char*)As + row*128 + byo);
      }
    }
    #pragma unroll
    for (int fc=0; fc<4; ++fc){
      int row = wc*64 + fc*16 + l15;
      #pragma unroll
      for (int ks=0; ks<2; ++ks){
        int byo = (l4*16 + ks*64) ^ ((row&7)<<4);
        bf_[fc][ks] = *(const bhalf8*)((const char*)Bs + row*128 + byo);
      }
    }
    #pragma unroll
    for (int ks=0; ks<2; ++ks)
      #pragma unroll
      for (int fr=0; fr<4; ++fr)
        #pragma unroll
        for (int fc=0; fc<4; ++fc)
          acc[fr][fc] = __builtin_amdgcn_mfma_f32_16x16x32_bf16(af[fr][ks], bf_[fc][ks], acc[fr][fc], 0, 0, 0);
  }

  const int rowBase = bm*128 + wr*64;
  const int colBase = bn*128 + wc*64;
  #pragma unroll
  for (int fc=0; fc<4; ++fc){
    int col = colBase + fc*16 + l15;
    float bv = bias[col];
    #pragma unroll
    for (int fr=0; fr<4; ++fr){
      #pragma unroll
      for (int j=0; j<4; ++j){
        int row = rowBase + fr*16 + l4*4 + j;
        float v = acc[fr][fc][j] + bv;
        if (ACT) v = fmaxf(v, 0.f);
        if (OUTB) Yb[(size_t)row*Nd + col] = f2b(v);
        else      Yf[(size_t)row*Nd + col] = v;
      }
    }
  }
}

// ---------- bf16 MFMA GEMM 128x64 (N=512 shapes), XCD-swizzled ----------
template<int ACT, int FUSE2, int OUTB>
__global__ __launch_bounds__(256) void mgemm64_k(const unsigned short* __restrict__ A,
    const unsigned short* __restrict__ W0, const unsigned short* __restrict__ W1v,
    const float* __restrict__ bias0, const float* __restrict__ bias1,
    float* __restrict__ Y0, float* __restrict__ Y1,
    unsigned short* __restrict__ Yb0, unsigned short* __restrict__ Yb1,
    int Nd, int K){
  __shared__ unsigned short As[128*64];
  __shared__ unsigned short Bs[64*64];
  const int tid = threadIdx.x;
  const int w = tid>>6, lane = tid&63;
  const int l15 = lane&15, l4 = lane>>4;
  const int wr = w>>1, wc = w&1;
  const int nwg = gridDim.x*gridDim.y;
  const int orig = blockIdx.y*gridDim.x + blockIdx.x;
  const int swz = (orig&7)*(nwg>>3) + (orig>>3);
  int bn = swz % gridDim.x;
  const int bm = swz / gridDim.x;
  const unsigned short* W = W0;
  const float* bias = bias0;
  float* Yf = Y0;
  unsigned short* Yb = Yb0;
  if (FUSE2 && bn >= 8){ W = W1v; bias = bias1; Yf = Y1; Yb = Yb1; bn -= 8; }

  const size_t Kb = (size_t)K*2;
  const int srow  = lane>>3;
  const int sbyte = ((lane&7)*16) ^ (srow<<4);
  const char* Ag = (const char*)A + (size_t)(bm*128)*Kb + sbyte;
  const char* Wg = (const char*)W + (size_t)(bn*64)*Kb + sbyte;

  f32x4 acc[4][2];
  const f32x4 z = {0.f,0.f,0.f,0.f};
  #pragma unroll
  for (int i=0;i<4;++i)
    #pragma unroll
    for (int j=0;j<2;++j) acc[i][j] = z;

  const int KT = K/64;
  for (int kt=0; kt<KT; ++kt){
    if (kt) __syncthreads();
    const size_t kOff = (size_t)kt*128;
    #pragma unroll
    for (int i=0;i<4;++i){
      int c = w*4 + i;
      int r = c*8 + srow;
      gll16(Ag + (size_t)r*Kb + kOff, (char*)As + c*1024);
    }
    #pragma unroll
    for (int i=0;i<2;++i){
      int c = w*2 + i;
      int r = c*8 + srow;
      gll16(Wg + (size_t)r*Kb + kOff, (char*)Bs + c*1024);
    }
    __syncthreads();

    bhalf8 af[4][2], bf_[2][2];
    #pragma unroll
    for (int fr=0; fr<4; ++fr){
      int row = wr*64 + fr*16 + l15;
      #pragma unroll
      for (int ks=0; ks<2; ++ks){
        int byo = (l4*16 + ks*64) ^ ((row&7)<<4);
        af[fr][ks] = *(const bhalf8*)((const char*)As + row*128 + byo);
      }
    }
    #pragma unroll
    for (int fc=0; fc<2; ++fc){
      int row = wc*32 + fc*16 + l15;
      #pragma unroll
      for (int ks=0; ks<2; ++ks){
        int byo = (l4*16 + ks*64) ^ ((row&7)<<4);
        bf_[fc][ks] = *(const bhalf8*)((const char*)Bs + row*128 + byo);
      }
    }
    #pragma unroll
    for (int ks=0; ks<2; ++ks)
      #pragma unroll
      for (int fr=0; fr<4; ++fr)
        #pragma unroll
        for (int fc=0; fc<2; ++fc)
          acc[fr][fc] = __builtin_amdgcn_mfma_f32_16x16x32_bf16(af[fr][ks], bf_[fc][ks], acc[fr][fc], 0, 0, 0);
  }

  const int rowBase = bm*128 + wr*64;
  const int colBase = bn*64 + wc*32;
  #pragma unroll
  for (int fc=0; fc<2; ++fc){
    int col = colBase + fc*16 + l15;
    float bv = bias[col];
    #pragma unroll
    for (int fr=0; fr<4; ++fr){
      #pragma unroll
      for (int j=0; j<4; ++j){
        int row = rowBase + fr*16 + l4*4 + j;
        float v = acc[fr][fc][j] + bv;
        if (ACT) v = fmaxf(v, 0.f);
        if (OUTB) Yb[(size_t)row*Nd + col] = f2b(v);
        else      Yf[(size_t)row*Nd + col] = v;
      }
    }
  }
}

// ---------- bf16 MFMA flash attention (R9 structure + XCD swizzle) ----------
__global__ __launch_bounds__(512, 4) void fattn_k(const unsigned short* __restrict__ qkv,
                                                  unsigned short* __restrict__ ao){
  __shared__ unsigned short Ks[2][64*64];
  __shared__ unsigned short Vt[2][64*64];
  __shared__ unsigned short Ps[128*64];
  const int nwg = gridDim.x*gridDim.y*gridDim.z;   // 512
  const int orig = (blockIdx.z*gridDim.y + blockIdx.y)*gridDim.x + blockIdx.x;
  const int swz = (orig&7)*(nwg>>3) + (orig>>3);
  const int qt = swz % gridDim.x;
  const int rem = swz / gridDim.x;
  const int h = rem % gridDim.y;
  const int b = rem / gridDim.y;
  const int tid = threadIdx.x, w = tid>>6, lane = tid&63;
  const int l15 = lane&15, l4 = lane>>4;
  const size_t rowB = 3072;
  const char* base = (const char*)qkv + (size_t)b*SEQ*rowB;
  const char* Kg = base + 1024 + h*128;
  const char* Vg = base + 2048 + h*128;
  const float C2 = 0.18033688f;             // 0.125 * log2(e)

  bhalf8 qf[2];
  {
    const char* qrow = base + (size_t)(qt*128 + w*16 + l15)*rowB + h*128;
    qf[0] = *(const bhalf8*)(qrow + l4*16);
    qf[1] = *(const bhalf8*)(qrow + l4*16 + 64);
  }
  bhalf8 v1;
  {
    short o = (l15==0) ? (short)0x3F80 : (short)0;
    v1 = (bhalf8){o,o,o,o,o,o,o,o};
  }

  const f32x4 z = {0.f,0.f,0.f,0.f};
  f32x4 oa[4], ol = z;
  #pragma unroll
  for (int i=0;i<4;++i) oa[i] = z;
  float mj = -INFINITY;

  const int srow  = lane>>3;
  const int sbyte = ((lane&7)*16) ^ (srow<<4);
  const int vd = lane;
  const int vsel = (vd>>3)&1;

  unsigned short vload[8];
  {
    int r = w*8 + srow;
    gll16(Kg + (size_t)r*rowB + sbyte, (char*)Ks[0] + w*1024);
  }
  #pragma unroll
  for (int i=0;i<8;++i)
    vload[i] = *(const unsigned short*)(Vg + (size_t)(w*8 + i)*rowB + vd*2);

  int cur = 0;
  for (int kt=0; kt<SEQ/64; ++kt){
    #pragma unroll
    for (int i=0;i<2;++i){
      int p = i ^ vsel;
      unsigned lo = (unsigned)vload[p*4+0] | ((unsigned)vload[p*4+1]<<16);
      unsigned hi = (unsigned)vload[p*4+2] | ((unsigned)vload[p*4+3]<<16);
      uint2 pk; pk.x = lo; pk.y = hi;
      int byo = (w*16 + p*8) ^ ((vd&7)<<4);
      *(uint2*)((char*)Vt[cur] + vd*128 + byo) = pk;
    }
    __syncthreads();

    if (kt+1 < SEQ/64){
      int r = w*8 + srow;
      gll16(Kg + (size_t)((kt+1)*64 + r)*rowB + sbyte, (char*)Ks[cur^1] + w*1024);
      #pragma unroll
      for (int i=0;i<8;++i)
        vload[i] = *(const unsigned short*)(Vg + (size_t)((kt+1)*64 + w*8 + i)*rowB + vd*2);
    }

    bhalf8 kf[4][2];
    #pragma unroll
    for (int fc=0; fc<4; ++fc){
      int kr = fc*16 + l15;
      #pragma unroll
      for (int ks=0; ks<2; ++ks){
        int byo = (l4*16 + ks*64) ^ ((kr&7)<<4);
        kf[fc][ks] = *(const bhalf8*)((const char*)Ks[cur] + kr*128 + byo);
      }
    }
    f32x4 s[4];
    #pragma unroll
    for (int i=0;i<4;++i) s[i] = z;
    __builtin_amdgcn_s_setprio(1);
    #pragma unroll
    for (int ks=0; ks<2; ++ks)
      #pragma unroll
      for (int fc=0; fc<4; ++fc)
        s[fc] = __builtin_amdgcn_mfma_f32_16x16x32_bf16(kf[fc][ks], qf[ks], s[fc], 0, 0, 0);
    __builtin_amdgcn_s_setprio(0);

    {
      float rm0 = fmaxf(fmaxf(s[0][0],s[0][1]), fmaxf(s[0][2],s[0][3]));
      float rm1 = fmaxf(fmaxf(s[1][0],s[1][1]), fmaxf(s[1][2],s[1][3]));
      float rm2 = fmaxf(fmaxf(s[2][0],s[2][1]), fmaxf(s[2][2],s[2][3]));
      float rm3 = fmaxf(fmaxf(s[3][0],s[3][1]), fmaxf(s[3][2],s[3][3]));
      float rm = fmaxf(fmaxf(rm0,rm1), fmaxf(rm2,rm3));
      rm = fmaxf(rm, __shfl_xor(rm,16));
      rm = fmaxf(rm, __shfl_xor(rm,32));
      float tmax = rm * C2;
      if (__any(tmax > mj + 8.f)){
        float mn = fmaxf(mj, tmax);
        float sc = exp2_hw(mj - mn);
        mj = mn;
        float scj0 = __shfl(sc, l4*4+0), scj1 = __shfl(sc, l4*4+1);
        float scj2 = __shfl(sc, l4*4+2), scj3 = __shfl(sc, l4*4+3);
        #pragma unroll
        for (int fc=0; fc<4; ++fc){
          oa[fc][0] *= scj0; oa[fc][1] *= scj1;
          oa[fc][2] *= scj2; oa[fc][3] *= scj3;
        }
        ol[0] *= scj0; ol[1] *= scj1; ol[2] *= scj2; ol[3] *= scj3;
      }
      int qrow = w*16 + l15;
      #pragma unroll
      for (int fc=0; fc<4; ++fc){
        float p0 = exp2_hw(fmaf(C2, s[fc][0], -mj));
        float p1 = exp2_hw(fmaf(C2, s[fc][1], -mj));
        float p2 = exp2_hw(fmaf(C2, s[fc][2], -mj));
        float p3 = exp2_hw(fmaf(C2, s[fc][3], -mj));
        unsigned lo, hi;
        asm volatile("v_cvt_pk_bf16_f32 %0, %1, %2" : "=v"(lo) : "v"(p0), "v"(p1));
        asm volatile("v_cvt_pk_bf16_f32 %0, %1, %2" : "=v"(hi) : "v"(p2), "v"(p3));
        uint2 pk; pk.x = lo; pk.y = hi;
        int byo = (fc*32 + l4*8) ^ ((l15&7)<<4);
        *(uint2*)((char*)Ps + qrow*128 + byo) = pk;
      }
    }

    bhalf8 vf[4][2];
    #pragma unroll
    for (int fc=0; fc<4; ++fc){
      int d = fc*16 + l15;
      #pragma unroll
      for (int ks=0; ks<2; ++ks){
        int byo = (ks*64 + l4*16) ^ ((d&7)<<4);
        vf[fc][ks] = *(const bhalf8*)((const char*)Vt[cur] + d*128 + byo);
      }
    }
    {
      int qrow = w*16 + l15;
      bhalf8 pf[2];
      #pragma unroll
      for (int ks=0; ks<2; ++ks){
        int byo = (ks*64 + l4*16) ^ ((l15&7)<<4);
        pf[ks] = *(const bhalf8*)((const char*)Ps + qrow*128 + byo);
      }
      __builtin_amdgcn_s_setprio(1);
      #pragma unroll
      for (int ks=0; ks<2; ++ks){
        #pragma unroll
        for (int fc=0; fc<4; ++fc)
          oa[fc] = __builtin_amdgcn_mfma_f32_16x16x32_bf16(pf[ks], vf[fc][ks], oa[fc], 0, 0, 0);
        ol = __builtin_amdgcn_mfma_f32_16x16x32_bf16(pf[ks], v1, ol, 0, 0, 0);
      }
      __builtin_amdgcn_s_setprio(0);
    }
    cur ^= 1;
  }

  {
    float li[4];
    #pragma unroll
    for (int j=0;j<4;++j) li[j] = 1.f/__shfl(ol[j], l4<<4);
    #pragma unroll
    for (int fc=0; fc<4; ++fc){
      int col = h*64 + fc*16 + l15;
      size_t r0 = (size_t)(b*SEQ + qt*128 + w*16 + l4*4);
      ao[(r0+0)*D_MODEL + col] = f2b(oa[fc][0]*li[0]);
      ao[(r0+1)*D_MODEL + col] = f2b(oa[fc][1]*li[1]);
      ao[(r0+2)*D_MODEL + col] = f2b(oa[fc][2]*li[2]);
      ao[(r0+3)*D_MODEL + col] = f2b(oa[fc][3]*li[3]);
    }
  }
}

// ---------- final LN: out = LN(A + bf16 B), single-pass ----------
__global__ __launch_bounds__(256) void lnfin_k(const float* __restrict__ A,
    const unsigned short* __restrict__ Bp,
    const float* __restrict__ g, const float* __restrict__ be, float* __restrict__ outf){
  __shared__ float lds[16];
  const size_t off = (size_t)blockIdx.x * D_MODEL;
  const int tid = threadIdx.x;
  float a0 = A[off+tid]     + b2f(Bp[off+tid]);
  float a1 = A[off+tid+256] + b2f(Bp[off+tid+256]);
  float s1 = a0+a1, s2 = a0*a0+a1*a1;
  block_sum2(s1, s2, lds);
  float mean = s1 * (1.f/512.f);
  float var  = s2 * (1.f/512.f) - mean*mean;
  float rstd = rsqrtf(var + 1e-5f);
  outf[off+tid]     = (a0-mean)*rstd*g[tid]     + be[tid];
  outf[off+tid+256] = (a1-mean)*rstd*g[tid+256] + be[tid+256];
}

// ---------- fused: x1 = LN(A+B); scan prep (bf16 dec/u out), single-pass ----------
__global__ __launch_bounds__(256) void ln_scan_k(const float* __restrict__ A, const float* __restrict__ Bp,
    const float* __restrict__ g, const float* __restrict__ be, const float* __restrict__ tm,
    float* __restrict__ x1out, unsigned short* __restrict__ dec, unsigned short* __restrict__ u,
    float* __restrict__ dm, float* __restrict__ es){
  __shared__ float lds[16];
  const size_t row = blockIdx.x;
  const size_t off = row * D_MODEL;
  const int tid = threadIdx.x;
  float a0 = A[off+tid] + Bp[off+tid];
  float a1 = A[off+tid+256] + Bp[off+tid+256];
  float s1 = a0+a1, s2 = a0*a0+a1*a1;
  block_sum2(s1, s2, lds);
  float mean = s1 * (1.f/512.f);
  float var  = s2 * (1.f/512.f) - mean*mean;
  float rstd = rsqrtf(var + 1e-5f);
  float r0 = (a0-mean)*rstd*g[tid]     + be[tid];
  float r1 = (a1-mean)*rstd*g[tid+256] + be[tid+256];
  x1out[off+tid] = r0; x1out[off+tid+256] = r1;
  float dc0 = sigmoidf_(r0*tm[tid]), dc1 = sigmoidf_(r1*tm[tid+256]);
  float e0 = expf(r0), e1 = expf(r1);
  dec[off+tid]=f2b(dc0); dec[off+tid+256]=f2b(dc1);
  u[off+tid]=f2b(e0*r0); u[off+tid+256]=f2b(e1*r1);
  float dsum = dc0+dc1, esum = e0+e1;
  block_sum2(dsum, esum, lds);
  if (tid==0){ dm[row]=dsum*(1.f/512.f); es[row]=esum; }
}

// ---------- fused: coupled = LN(sigmoid(R)*V); x2 = LN(X1+coupled); bf16 R,V in ----------
__global__ __launch_bounds__(256) void ln2x_k(const unsigned short* __restrict__ R,
    const unsigned short* __restrict__ V, const float* __restrict__ X1,
    const float* __restrict__ g1, const float* __restrict__ b1_,
    const float* __restrict__ g2, const float* __restrict__ b2_,
    float* __restrict__ x2f, unsigned short* __restrict__ x2b){
  __shared__ float lds[16];
  const size_t off = (size_t)blockIdx.x * D_MODEL;
  const int tid = threadIdx.x;
  float a0 = sigmoidf_(b2f(R[off+tid]))*b2f(V[off+tid]);
  float a1 = sigmoidf_(b2f(R[off+tid+256]))*b2f(V[off+tid+256]);
  float s1 = a0+a1, s2 = a0*a0+a1*a1;
  block_sum2(s1, s2, lds);
  float mean = s1*(1.f/512.f);
  float var  = s2*(1.f/512.f) - mean*mean;
  float rstd = rsqrtf(var + 1e-5f);
  float c0 = (a0-mean)*rstd*g1[tid]     + b1_[tid];
  float c1 = (a1-mean)*rstd*g1[tid+256] + b1_[tid+256];
  float t0 = X1[off+tid] + c0, t1 = X1[off+tid+256] + c1;
  float u1 = t0+t1, u2 = t0*t0+t1*t1;
  block_sum2(u1, u2, lds);
  float mean2 = u1*(1.f/512.f);
  float var2  = u2*(1.f/512.f) - mean2*mean2;
  float rstd2 = rsqrtf(var2 + 1e-5f);
  float r0 = (t0-mean2)*rstd2*g2[tid]     + b2_[tid];
  float r1 = (t1-mean2)*rstd2*g2[tid+256] + b2_[tid+256];
  x2f[off+tid] = r0; x2f[off+tid+256] = r1;
  x2b[off+tid] = f2b(r0); x2b[off+tid+256] = f2b(r1);
}

// ---------- b scan phase 1 (bf16 in) ----------
__global__ __launch_bounds__(512) void bscan_p1(const unsigned short* __restrict__ decay,
    const unsigned short* __restrict__ u, float* __restrict__ Gc, float* __restrict__ Uc){
  const int c = blockIdx.x, b = blockIdx.y, d = threadIdx.x;
  size_t base = ((size_t)b*SEQ + (size_t)c*CHUNK)*D_MODEL + d;
  float G=1.f, U=0.f;
  for (int i=0;i<CHUNK;++i){
    float g  = b2f(decay[base + (size_t)i*D_MODEL]);
    float uu = b2f(u[base + (size_t)i*D_MODEL]);
    U = g*U + uu; G = g*G;
  }
  size_t idx = ((size_t)b*NCHUNK + c)*D_MODEL + d;
  Gc[idx]=G; Uc[idx]=U;
}

// ---------- merged: b-scan phase 2 (blocks 0-3) + 'a' scan (blocks 4-7) ----------
__global__ __launch_bounds__(512) void scan2_k(const float* __restrict__ Gc, const float* __restrict__ Uc,
    float* __restrict__ binit, const float* __restrict__ dm, const float* __restrict__ es,
    float* __restrict__ a_out){
  __shared__ float sG[512], sU[512];
  if (blockIdx.x < 4){
    const int b = blockIdx.x, d = threadIdx.x;
    float cur = 0.f;
    for (int c=0;c<NCHUNK;++c){
      size_t idx = ((size_t)b*NCHUNK + c)*D_MODEL + d;
      binit[idx] = cur;
      cur = Gc[idx]*cur + Uc[idx];
    }
  } else {
    const int b = blockIdx.x - 4, tid = threadIdx.x;
    const float* dmb = dm + (size_t)b*SEQ;
    const float* esb = es + (size_t)b*SEQ;
    const int t0 = tid*4;
    float gi[4], ui[4];
    #pragma unroll
    for (int i=0;i<4;++i){ gi[i]=dmb[t0+i]; ui[i]=esb[t0+i]; }
    float G=1.f, U=0.f;
    #pragma unroll
    for (int i=0;i<4;++i){ U = gi[i]*U + ui[i]; G *= gi[i]; }
    sG[tid]=G; sU[tid]=U;
    __syncthreads();
    for (int off=1; off<512; off<<=1){
      float pg=1.f, pu=0.f;
      bool act = tid >= off;
      if (act){ pg = sG[tid-off]; pu = sU[tid-off]; }
      __syncthreads();
      if (act){ sU[tid] = sG[tid]*pu + sU[tid]; sG[tid] = sG[tid]*pg; }
      __syncthreads();
    }
    float a = (tid==0) ? 0.f : sU[tid-1];
    #pragma unroll
    for (int i=0;i<4;++i){ a = gi[i]*a + ui[i]; a_out[(size_t)b*SEQ + t0 + i] = a; }
  }
}

// ---------- fused p3 + LN(merged), bf16 in, single-pass LN ----------
__global__ __launch_bounds__(512) void p3ln_k(const unsigned short* __restrict__ decay,
    const unsigned short* __restrict__ u,
    const float* __restrict__ binit, const float* __restrict__ a,
    const float* __restrict__ g, const float* __restrict__ be,
    unsigned short* __restrict__ mb){
  __shared__ float lds[16];
  const int c = blockIdx.x, b = blockIdx.y, d = threadIdx.x;
  size_t base = ((size_t)b*SEQ + (size_t)c*CHUNK)*D_MODEL + d;
  float bv = binit[((size_t)b*NCHUNK + c)*D_MODEL + d];
  float gg = g[d], bb = be[d];
  for (int i=0;i<CHUNK;++i){
    float gd = b2f(decay[base + (size_t)i*D_MODEL]);
    float uu = b2f(u[base + (size_t)i*D_MODEL]);
    bv = gd*bv + uu;
    float av = a[(size_t)b*SEQ + (size_t)c*CHUNK + i];
    float val = bv / (av + 1e-8f);
    float s1 = val, s2 = val*val;
    block_sum2(s1, s2, lds);
    float mean = s1*(1.f/512.f);
    float var  = s2*(1.f/512.f) - mean*mean;
    float rstd = rsqrtf(var + 1e-5f);
    mb[base + (size_t)i*D_MODEL] = f2b((val-mean)*rstd*gg + bb);
  }
}

extern "C" void kernel_launch(void* const* d_in, const int* in_sizes, int n_in,
                              void* d_out, int out_size, void* d_ws, size_t ws_size,
                              hipStream_t stream){
  const float* x     = (const float*)d_in[0];
  const float* xp    = (const float*)d_in[1];
  const float* mu    = (const float*)d_in[2];
  const float* in_w  = (const float*)d_in[3];
  const float* in_b  = (const float*)d_in[4];
  const float* out_w = (const float*)d_in[5];
  const float* out_b = (const float*)d_in[6];
  const float* ln1_g = (const float*)d_in[7];
  const float* ln1_b = (const float*)d_in[8];
  const float* tm    = (const float*)d_in[9];
  const float* sm_g  = (const float*)d_in[10];
  const float* sm_b  = (const float*)d_in[11];
  const float* wr_w  = (const float*)d_in[12];
  const float* wr_b  = (const float*)d_in[13];
  const float* wv_w  = (const float*)d_in[14];
  const float* wv_b  = (const float*)d_in[15];
  const float* sc_g  = (const float*)d_in[16];
  const float* sc_b  = (const float*)d_in[17];
  const float* ln2_g = (const float*)d_in[18];
  const float* ln2_b = (const float*)d_in[19];
  const float* w1    = (const float*)d_in[20];
  const float* b1    = (const float*)d_in[21];
  const float* w2    = (const float*)d_in[22];
  const float* b2    = (const float*)d_in[23];
  const float* ln3_g = (const float*)d_in[24];
  const float* ln3_b = (const float*)d_in[25];
  float* out = (float*)d_out;
  float* ws  = (float*)d_ws;

  const size_t N = (size_t)M_TOK*D_MODEL;   // 4,194,304
  float* S0f = ws;
  float* S1f = ws + N;
  float* S2f = ws + 2*N;
  float* EX  = ws + 3*N;
  float* dm    = EX;
  float* es    = EX + 8192;
  float* aarr  = EX + 16384;
  float* Gc    = EX + 24576;
  float* Uc    = Gc + 131072;
  float* binit = Uc + 131072;

  unsigned short* SB = (unsigned short*)(ws + 3*N + N/4);
  unsigned short* Wq = SB;
  unsigned short* Wo = Wq + 786432;
  unsigned short* Wr = Wo + 262144;
  unsigned short* Wv = Wr + 262144;
  unsigned short* W1 = Wv + 262144;
  unsigned short* W2 = W1 + 1048576;
  unsigned short* Xb = W2 + 1048576;
  unsigned short* Mb = Xb + N;
  unsigned short* U  = Mb + N;
  unsigned short* Qb  = U;
  unsigned short* AOb = U + 12*1024*1024;
  unsigned short* ub   = U;                    // after Qb dead
  unsigned short* decb = U + 12*1024*1024;     // after AOb dead
  unsigned short* Rb   = U;                    // after ub dead
  unsigned short* Vb   = U + 4*1024*1024;
  unsigned short* Hb   = U;                    // FFN hidden
  unsigned short* Fb   = Mb;                   // FFN2 out (Mb dead)

  // 0. weight converts + shift (one launch)
  cvtshift_k<<<7680, 256, 0, stream>>>(in_w, out_w, wr_w, wv_w, w1, w2,
                                       Wq, Wo, Wr, Wv, W1, W2,
                                       x, xp, mu, S0f, Xb);
  // 1. qkv -> Qb
  mgemm_k<0,1><<<dim3(12,64), 256, 0, stream>>>(Xb, Wq, in_b, nullptr, Qb, 1536, 512);
  // 2. flash attention -> AOb
  fattn_k<<<dim3(SEQ/128, NH, BATCH), 512, 0, stream>>>(Qb, AOb);
  // 3. out-proj -> S1f
  mgemm64_k<0,0,0><<<dim3(8,64), 256, 0, stream>>>(AOb, Wo, nullptr, out_b, nullptr,
                                                   S1f, nullptr, nullptr, nullptr, 512, 512);
  // 4. x1 = LN(shifted+proj) -> S2f; decb/ub (bf16); dm/es
  ln_scan_k<<<M_TOK, 256, 0, stream>>>(S0f, S1f, ln1_g, ln1_b, tm, S2f, decb, ub, dm, es);
  // 5. b-scan phase 1
  bscan_p1<<<dim3(NCHUNK, BATCH), 512, 0, stream>>>(decb, ub, Gc, Uc);
  // 6. merged p2 + ascan
  scan2_k<<<8, 512, 0, stream>>>(Gc, Uc, binit, dm, es, aarr);
  // 7. p3 + LN(merged) -> Mb
  p3ln_k<<<dim3(NCHUNK, BATCH), 512, 0, stream>>>(decb, ub, binit, aarr, sm_g, sm_b, Mb);
  // 8. r -> Rb, v -> Vb (bf16, fused)
  mgemm64_k<0,1,1><<<dim3(16,64), 256, 0, stream>>>(Mb, Wr, Wv, wr_b, wv_b,
                                                    nullptr, nullptr, Rb, Vb, 512, 512);
  // 9. coupled-LN + x2-LN -> S0f + Xb
  ln2x_k<<<M_TOK, 256, 0, stream>>>(Rb, Vb, S2f, sc_g, sc_b, ln2_g, ln2_b, S0f, Xb);
  // 10. hidden = relu(x2 @ w1.T + b1) -> Hb
  mgemm_k<1,1><<<dim3(16,64), 256, 0, stream>>>(Xb, W1, b1, nullptr, Hb, 2048, 512);
  // 11. ffnout -> Fb (bf16)
  mgemm64_k<0,0,1><<<dim3(8,64), 256, 0, stream>>>(Hb, W2, nullptr, b2, nullptr,
                                                   nullptr, nullptr, Fb, nullptr, 512, 2048);
  // 12. out = LN(x2 + ffnout)
  lnfin_k<<<M_TOK, 256, 0, stream>>>(S0f, Fb, ln3_g, ln3_b, out);
}

// Round 11
// 252.286 us; speedup vs baseline: 1.3941x; 1.0385x over previous
//
#include <hip/hip_runtime.h>
#include <math.h>

#define D_MODEL 512
#define SEQ     2048
#define BATCH   4
#define NH      8
#define HD      64
#define CHUNK   32
#define NCHUNK  64
#define M_TOK   (BATCH*SEQ)   // 8192

typedef __attribute__((ext_vector_type(8))) short bhalf8;   // 8 bf16 = 4 VGPR
typedef __attribute__((ext_vector_type(4))) float f32x4;

__device__ __forceinline__ float sigmoidf_(float x){ return 1.f/(1.f+expf(-x)); }

__device__ __forceinline__ unsigned short f2b(float f){   // fp32 -> bf16 RNE
  unsigned u = __float_as_uint(f);
  u += 0x7FFFu + ((u>>16)&1u);
  return (unsigned short)(u>>16);
}
__device__ __forceinline__ float b2f(unsigned short h){
  return __uint_as_float(((unsigned)h)<<16);
}
__device__ __forceinline__ float blo(unsigned v){ return __uint_as_float(v<<16); }
__device__ __forceinline__ float bhi(unsigned v){ return __uint_as_float(v & 0xFFFF0000u); }
__device__ __forceinline__ unsigned bpack(float a, float b){
  return (unsigned)f2b(a) | ((unsigned)f2b(b)<<16);
}

__device__ __forceinline__ void gll16(const void* g, void* l){
  __builtin_amdgcn_global_load_lds(
      (const __attribute__((address_space(1))) unsigned int*)g,
      (__attribute__((address_space(3))) unsigned int*)l, 16, 0, 0);
}

__device__ __forceinline__ float exp2_hw(float x){
  float r;
  asm volatile("v_exp_f32 %0, %1" : "=v"(r) : "v"(x));
  return r;
}

// ---------- paired block reduction: one barrier round for two sums ----------
__device__ __forceinline__ void block_sum2(float& a, float& b, float* lds){
  #pragma unroll
  for (int o=32;o>0;o>>=1){ a += __shfl_xor(a,o); b += __shfl_xor(b,o); }
  int w = threadIdx.x>>6, l = threadIdx.x&63;
  if (l==0){ lds[2*w]=a; lds[2*w+1]=b; }
  __syncthreads();
  float ta=0.f, tb=0.f; int nw = blockDim.x>>6;
  for (int i=0;i<nw;++i){ ta+=lds[2*i]; tb+=lds[2*i+1]; }
  a=ta; b=tb;
  __syncthreads();
}

// ---------- merged: weight converts + shift (bf16 out only) ----------
__global__ void cvtshift_k(const float* __restrict__ s0,const float* __restrict__ s1,
                           const float* __restrict__ s2,const float* __restrict__ s3,
                           const float* __restrict__ s4,const float* __restrict__ s5,
                           unsigned short* __restrict__ d0,unsigned short* __restrict__ d1,
                           unsigned short* __restrict__ d2,unsigned short* __restrict__ d3,
                           unsigned short* __restrict__ d4,unsigned short* __restrict__ d5,
                           const float* __restrict__ x, const float* __restrict__ xp,
                           const float* __restrict__ mu,
                           unsigned short* __restrict__ ob){
  int t = blockIdx.x*blockDim.x + threadIdx.x;
  if (t < 917504){
    int j = t;
    const float* s; unsigned short* d;
    if (j < 196608){ s=s0; d=d0; }
    else if ((j-=196608) < 65536){ s=s1; d=d1; }
    else if ((j-=65536)  < 65536){ s=s2; d=d2; }
    else if ((j-=65536)  < 65536){ s=s3; d=d3; }
    else if ((j-=65536)  < 262144){ s=s4; d=d4; }
    else { j-=262144; s=s5; d=d5; }
    float4 v = ((const float4*)s)[j];
    uint2 p; p.x = bpack(v.x, v.y); p.y = bpack(v.z, v.w);
    ((uint2*)d)[j] = p;
  } else {
    int i = t - 917504;   // 0 .. 1048575
    float m = mu[0];
    float4 a = ((const float4*)x)[i], p = ((const float4*)xp)[i];
    float4 r;
    r.x = m*a.x + (1.f-m)*p.x; r.y = m*a.y + (1.f-m)*p.y;
    r.z = m*a.z + (1.f-m)*p.z; r.w = m*a.w + (1.f-m)*p.w;
    uint2 q; q.x = bpack(r.x, r.y); q.y = bpack(r.z, r.w);
    ((uint2*)ob)[i] = q;
  }
}

// ---------- bf16 MFMA GEMM 128x128, XCD-swizzled (unchanged) ----------
template<int ACT, int OUTB>
__global__ __launch_bounds__(256) void mgemm_k(const unsigned short* __restrict__ A,
    const unsigned short* __restrict__ W, const float* __restrict__ bias,
    float* __restrict__ Yf, unsigned short* __restrict__ Yb, int Nd, int K){
  __shared__ unsigned short As[128*64];
  __shared__ unsigned short Bs[128*64];
  const int tid = threadIdx.x;
  const int w = tid>>6, lane = tid&63;
  const int l15 = lane&15, l4 = lane>>4;
  const int wr = w>>1, wc = w&1;
  const int nwg = gridDim.x*gridDim.y;
  const int orig = blockIdx.y*gridDim.x + blockIdx.x;
  const int swz = (orig&7)*(nwg>>3) + (orig>>3);
  const int bn = swz % gridDim.x;
  const int bm = swz / gridDim.x;

  const size_t Kb = (size_t)K*2;
  const int srow  = lane>>3;
  const int sbyte = ((lane&7)*16) ^ (srow<<4);
  const char* Ag = (const char*)A + (size_t)(bm*128)*Kb + sbyte;
  const char* Wg = (const char*)W + (size_t)(bn*128)*Kb + sbyte;

  f32x4 acc[4][4];
  const f32x4 z = {0.f,0.f,0.f,0.f};
  #pragma unroll
  for (int i=0;i<4;++i)
    #pragma unroll
    for (int j=0;j<4;++j) acc[i][j] = z;

  const int KT = K/64;
  for (int kt=0; kt<KT; ++kt){
    if (kt) __syncthreads();
    const size_t kOff = (size_t)kt*128;
    #pragma unroll
    for (int i=0;i<4;++i){
      int c = w*4 + i;
      int r = c*8 + srow;
      gll16(Ag + (size_t)r*Kb + kOff, (char*)As + c*1024);
      gll16(Wg + (size_t)r*Kb + kOff, (char*)Bs + c*1024);
    }
    __syncthreads();

    bhalf8 af[4][2], bf_[4][2];
    #pragma unroll
    for (int fr=0; fr<4; ++fr){
      int row = wr*64 + fr*16 + l15;
      #pragma unroll
      for (int ks=0; ks<2; ++ks){
        int byo = (l4*16 + ks*64) ^ ((row&7)<<4);
        af[fr][ks] = *(const bhalf8*)((const char*)As + row*128 + byo);
      }
    }
    #pragma unroll
    for (int fc=0; fc<4; ++fc){
      int row = wc*64 + fc*16 + l15;
      #pragma unroll
      for (int ks=0; ks<2; ++ks){
        int byo = (l4*16 + ks*64) ^ ((row&7)<<4);
        bf_[fc][ks] = *(const bhalf8*)((const char*)Bs + row*128 + byo);
      }
    }
    #pragma unroll
    for (int ks=0; ks<2; ++ks)
      #pragma unroll
      for (int fr=0; fr<4; ++fr)
        #pragma unroll
        for (int fc=0; fc<4; ++fc)
          acc[fr][fc] = __builtin_amdgcn_mfma_f32_16x16x32_bf16(af[fr][ks], bf_[fc][ks], acc[fr][fc], 0, 0, 0);
  }

  const int rowBase = bm*128 + wr*64;
  const int colBase = bn*128 + wc*64;
  #pragma unroll
  for (int fc=0; fc<4; ++fc){
    int col = colBase + fc*16 + l15;
    float bv = bias[col];
    #pragma unroll
    for (int fr=0; fr<4; ++fr){
      #pragma unroll
      for (int j=0; j<4; ++j){
        int row = rowBase + fr*16 + l4*4 + j;
        float v = acc[fr][fc][j] + bv;
        if (ACT) v = fmaxf(v, 0.f);
        if (OUTB) Yb[(size_t)row*Nd + col] = f2b(v);
        else      Yf[(size_t)row*Nd + col] = v;
      }
    }
  }
}

// ---------- bf16 MFMA GEMM 128x64, XCD-swizzled; FUSE2 or SPLITK ----------
template<int ACT, int FUSE2, int SPLITK>
__global__ __launch_bounds__(256) void mgemm64_k(const unsigned short* __restrict__ A,
    const unsigned short* __restrict__ W0, const unsigned short* __restrict__ W1v,
    const float* __restrict__ bias0, const float* __restrict__ bias1,
    unsigned short* __restrict__ Yb0, unsigned short* __restrict__ Yb1,
    int Nd, int K){
  __shared__ unsigned short As[128*64];
  __shared__ unsigned short Bs[64*64];
  const int tid = threadIdx.x;
  const int w = tid>>6, lane = tid&63;
  const int l15 = lane&15, l4 = lane>>4;
  const int wr = w>>1, wc = w&1;
  const int nwg = gridDim.x*gridDim.y;
  const int orig = blockIdx.y*gridDim.x + blockIdx.x;
  const int swz = (orig&7)*(nwg>>3) + (orig>>3);
  int bn = swz % gridDim.x;
  const int bm = swz / gridDim.x;
  const unsigned short* W = W0;
  const float* bias = bias0;
  unsigned short* Yb = Yb0;
  int half = 0;
  if (FUSE2 && bn >= 8){ W = W1v; bias = bias1; Yb = Yb1; bn -= 8; }
  if (SPLITK && bn >= 8){ half = 1; Yb = Yb1; bn -= 8; }

  const int Ksr = SPLITK ? (K>>1) : K;          // reduction depth per block
  const size_t Kb = (size_t)K*2;                // row stride bytes
  const size_t hOff = (size_t)half * Ksr * 2;   // split-K column offset
  const int srow  = lane>>3;
  const int sbyte = ((lane&7)*16) ^ (srow<<4);
  const char* Ag = (const char*)A + (size_t)(bm*128)*Kb + hOff + sbyte;
  const char* Wg = (const char*)W + (size_t)(bn*64)*Kb + hOff + sbyte;

  f32x4 acc[4][2];
  const f32x4 z = {0.f,0.f,0.f,0.f};
  #pragma unroll
  for (int i=0;i<4;++i)
    #pragma unroll
    for (int j=0;j<2;++j) acc[i][j] = z;

  const int KT = Ksr/64;
  for (int kt=0; kt<KT; ++kt){
    if (kt) __syncthreads();
    const size_t kOff = (size_t)kt*128;
    #pragma unroll
    for (int i=0;i<4;++i){
      int c = w*4 + i;
      int r = c*8 + srow;
      gll16(Ag + (size_t)r*Kb + kOff, (char*)As + c*1024);
    }
    #pragma unroll
    for (int i=0;i<2;++i){
      int c = w*2 + i;
      int r = c*8 + srow;
      gll16(Wg + (size_t)r*Kb + kOff, (char*)Bs + c*1024);
    }
    __syncthreads();

    bhalf8 af[4][2], bf_[2][2];
    #pragma unroll
    for (int fr=0; fr<4; ++fr){
      int row = wr*64 + fr*16 + l15;
      #pragma unroll
      for (int ks=0; ks<2; ++ks){
        int byo = (l4*16 + ks*64) ^ ((row&7)<<4);
        af[fr][ks] = *(const bhalf8*)((const char*)As + row*128 + byo);
      }
    }
    #pragma unroll
    for (int fc=0; fc<2; ++fc){
      int row = wc*32 + fc*16 + l15;
      #pragma unroll
      for (int ks=0; ks<2; ++ks){
        int byo = (l4*16 + ks*64) ^ ((row&7)<<4);
        bf_[fc][ks] = *(const bhalf8*)((const char*)Bs + row*128 + byo);
      }
    }
    #pragma unroll
    for (int ks=0; ks<2; ++ks)
      #pragma unroll
      for (int fr=0; fr<4; ++fr)
        #pragma unroll
        for (int fc=0; fc<2; ++fc)
          acc[fr][fc] = __builtin_amdgcn_mfma_f32_16x16x32_bf16(af[fr][ks], bf_[fc][ks], acc[fr][fc], 0, 0, 0);
  }

  const int rowBase = bm*128 + wr*64;
  const int colBase = bn*64 + wc*32;
  #pragma unroll
  for (int fc=0; fc<2; ++fc){
    int col = colBase + fc*16 + l15;
    float bv = (SPLITK && half) ? 0.f : bias[col];
    #pragma unroll
    for (int fr=0; fr<4; ++fr){
      #pragma unroll
      for (int j=0; j<4; ++j){
        int row = rowBase + fr*16 + l4*4 + j;
        float v = acc[fr][fc][j] + bv;
        if (ACT) v = fmaxf(v, 0.f);
        Yb[(size_t)row*Nd + col] = f2b(v);
      }
    }
  }
}

// ---------- bf16 MFMA flash attention (unchanged from R10) ----------
__global__ __launch_bounds__(512, 4) void fattn_k(const unsigned short* __restrict__ qkv,
                                                  unsigned short* __restrict__ ao){
  __shared__ unsigned short Ks[2][64*64];
  __shared__ unsigned short Vt[2][64*64];
  __shared__ unsigned short Ps[128*64];
  const int nwg = gridDim.x*gridDim.y*gridDim.z;   // 512
  const int orig = (blockIdx.z*gridDim.y + blockIdx.y)*gridDim.x + blockIdx.x;
  const int swz = (orig&7)*(nwg>>3) + (orig>>3);
  const int qt = swz % gridDim.x;
  const int rem = swz / gridDim.x;
  const int h = rem % gridDim.y;
  const int b = rem / gridDim.y;
  const int tid = threadIdx.x, w = tid>>6, lane = tid&63;
  const int l15 = lane&15, l4 = lane>>4;
  const size_t rowB = 3072;
  const char* base = (const char*)qkv + (size_t)b*SEQ*rowB;
  const char* Kg = base + 1024 + h*128;
  const char* Vg = base + 2048 + h*128;
  const float C2 = 0.18033688f;             // 0.125 * log2(e)

  bhalf8 qf[2];
  {
    const char* qrow = base + (size_t)(qt*128 + w*16 + l15)*rowB + h*128;
    qf[0] = *(const bhalf8*)(qrow + l4*16);
    qf[1] = *(const bhalf8*)(qrow + l4*16 + 64);
  }
  bhalf8 v1;
  {
    short o = (l15==0) ? (short)0x3F80 : (short)0;
    v1 = (bhalf8){o,o,o,o,o,o,o,o};
  }

  const f32x4 z = {0.f,0.f,0.f,0.f};
  f32x4 oa[4], ol = z;
  #pragma unroll
  for (int i=0;i<4;++i) oa[i] = z;
  float mj = -INFINITY;

  const int srow  = lane>>3;
  const int sbyte = ((lane&7)*16) ^ (srow<<4);
  const int vd = lane;
  const int vsel = (vd>>3)&1;

  unsigned short vload[8];
  {
    int r = w*8 + srow;
    gll16(Kg + (size_t)r*rowB + sbyte, (char*)Ks[0] + w*1024);
  }
  #pragma unroll
  for (int i=0;i<8;++i)
    vload[i] = *(const unsigned short*)(Vg + (size_t)(w*8 + i)*rowB + vd*2);

  int cur = 0;
  for (int kt=0; kt<SEQ/64; ++kt){
    #pragma unroll
    for (int i=0;i<2;++i){
      int p = i ^ vsel;
      unsigned lo = (unsigned)vload[p*4+0] | ((unsigned)vload[p*4+1]<<16);
      unsigned hi = (unsigned)vload[p*4+2] | ((unsigned)vload[p*4+3]<<16);
      uint2 pk; pk.x = lo; pk.y = hi;
      int byo = (w*16 + p*8) ^ ((vd&7)<<4);
      *(uint2*)((char*)Vt[cur] + vd*128 + byo) = pk;
    }
    __syncthreads();

    if (kt+1 < SEQ/64){
      int r = w*8 + srow;
      gll16(Kg + (size_t)((kt+1)*64 + r)*rowB + sbyte, (char*)Ks[cur^1] + w*1024);
      #pragma unroll
      for (int i=0;i<8;++i)
        vload[i] = *(const unsigned short*)(Vg + (size_t)((kt+1)*64 + w*8 + i)*rowB + vd*2);
    }

    bhalf8 kf[4][2];
    #pragma unroll
    for (int fc=0; fc<4; ++fc){
      int kr = fc*16 + l15;
      #pragma unroll
      for (int ks=0; ks<2; ++ks){
        int byo = (l4*16 + ks*64) ^ ((kr&7)<<4);
        kf[fc][ks] = *(const bhalf8*)((const char*)Ks[cur] + kr*128 + byo);
      }
    }
    f32x4 s[4];
    #pragma unroll
    for (int i=0;i<4;++i) s[i] = z;
    __builtin_amdgcn_s_setprio(1);
    #pragma unroll
    for (int ks=0; ks<2; ++ks)
      #pragma unroll
      for (int fc=0; fc<4; ++fc)
        s[fc] = __builtin_amdgcn_mfma_f32_16x16x32_bf16(kf[fc][ks], qf[ks], s[fc], 0, 0, 0);
    __builtin_amdgcn_s_setprio(0);

    {
      float rm0 = fmaxf(fmaxf(s[0][0],s[0][1]), fmaxf(s[0][2],s[0][3]));
      float rm1 = fmaxf(fmaxf(s[1][0],s[1][1]), fmaxf(s[1][2],s[1][3]));
      float rm2 = fmaxf(fmaxf(s[2][0],s[2][1]), fmaxf(s[2][2],s[2][3]));
      float rm3 = fmaxf(fmaxf(s[3][0],s[3][1]), fmaxf(s[3][2],s[3][3]));
      float rm = fmaxf(fmaxf(rm0,rm1), fmaxf(rm2,rm3));
      rm = fmaxf(rm, __shfl_xor(rm,16));
      rm = fmaxf(rm, __shfl_xor(rm,32));
      float tmax = rm * C2;
      if (__any(tmax > mj + 8.f)){
        float mn = fmaxf(mj, tmax);
        float sc = exp2_hw(mj - mn);
        mj = mn;
        float scj0 = __shfl(sc, l4*4+0), scj1 = __shfl(sc, l4*4+1);
        float scj2 = __shfl(sc, l4*4+2), scj3 = __shfl(sc, l4*4+3);
        #pragma unroll
        for (int fc=0; fc<4; ++fc){
          oa[fc][0] *= scj0; oa[fc][1] *= scj1;
          oa[fc][2] *= scj2; oa[fc][3] *= scj3;
        }
        ol[0] *= scj0; ol[1] *= scj1; ol[2] *= scj2; ol[3] *= scj3;
      }
      int qrow = w*16 + l15;
      #pragma unroll
      for (int fc=0; fc<4; ++fc){
        float p0 = exp2_hw(fmaf(C2, s[fc][0], -mj));
        float p1 = exp2_hw(fmaf(C2, s[fc][1], -mj));
        float p2 = exp2_hw(fmaf(C2, s[fc][2], -mj));
        float p3 = exp2_hw(fmaf(C2, s[fc][3], -mj));
        unsigned lo, hi;
        asm volatile("v_cvt_pk_bf16_f32 %0, %1, %2" : "=v"(lo) : "v"(p0), "v"(p1));
        asm volatile("v_cvt_pk_bf16_f32 %0, %1, %2" : "=v"(hi) : "v"(p2), "v"(p3));
        uint2 pk; pk.x = lo; pk.y = hi;
        int byo = (fc*32 + l4*8) ^ ((l15&7)<<4);
        *(uint2*)((char*)Ps + qrow*128 + byo) = pk;
      }
    }

    bhalf8 vf[4][2];
    #pragma unroll
    for (int fc=0; fc<4; ++fc){
      int d = fc*16 + l15;
      #pragma unroll
      for (int ks=0; ks<2; ++ks){
        int byo = (ks*64 + l4*16) ^ ((d&7)<<4);
        vf[fc][ks] = *(const bhalf8*)((const char*)Vt[cur] + d*128 + byo);
      }
    }
    {
      int qrow = w*16 + l15;
      bhalf8 pf[2];
      #pragma unroll
      for (int ks=0; ks<2; ++ks){
        int byo = (ks*64 + l4*16) ^ ((l15&7)<<4);
        pf[ks] = *(const bhalf8*)((const char*)Ps + qrow*128 + byo);
      }
      __builtin_amdgcn_s_setprio(1);
      #pragma unroll
      for (int ks=0; ks<2; ++ks){
        #pragma unroll
        for (int fc=0; fc<4; ++fc)
          oa[fc] = __builtin_amdgcn_mfma_f32_16x16x32_bf16(pf[ks], vf[fc][ks], oa[fc], 0, 0, 0);
        ol = __builtin_amdgcn_mfma_f32_16x16x32_bf16(pf[ks], v1, ol, 0, 0, 0);
      }
      __builtin_amdgcn_s_setprio(0);
    }
    cur ^= 1;
  }

  {
    float li[4];
    #pragma unroll
    for (int j=0;j<4;++j) li[j] = 1.f/__shfl(ol[j], l4<<4);
    #pragma unroll
    for (int fc=0; fc<4; ++fc){
      int col = h*64 + fc*16 + l15;
      size_t r0 = (size_t)(b*SEQ + qt*128 + w*16 + l4*4);
      ao[(r0+0)*D_MODEL + col] = f2b(oa[fc][0]*li[0]);
      ao[(r0+1)*D_MODEL + col] = f2b(oa[fc][1]*li[1]);
      ao[(r0+2)*D_MODEL + col] = f2b(oa[fc][2]*li[2]);
      ao[(r0+3)*D_MODEL + col] = f2b(oa[fc][3]*li[3]);
    }
  }
}

// ---------- final LN: out = LN(x2b + F0 + F1), all bf16 in, fp32 out ----------
__global__ __launch_bounds__(256) void lnfin_k(const unsigned int* __restrict__ X2b,
    const unsigned int* __restrict__ F0, const unsigned int* __restrict__ F1,
    const float* __restrict__ g, const float* __restrict__ be, float* __restrict__ outf){
  __shared__ float lds[16];
  const size_t off2 = (size_t)blockIdx.x * 256;
  const int tid = threadIdx.x;
  unsigned xv = X2b[off2+tid], f0 = F0[off2+tid], f1 = F1[off2+tid];
  float a0 = blo(xv) + blo(f0) + blo(f1);
  float a1 = bhi(xv) + bhi(f0) + bhi(f1);
  float s1 = a0+a1, s2 = a0*a0+a1*a1;
  block_sum2(s1, s2, lds);
  float mean = s1 * (1.f/512.f);
  float var  = s2 * (1.f/512.f) - mean*mean;
  float rstd = rsqrtf(var + 1e-5f);
  float2 gg = ((const float2*)g)[tid], bb = ((const float2*)be)[tid];
  float2 r;
  r.x = (a0-mean)*rstd*gg.x + bb.x;
  r.y = (a1-mean)*rstd*gg.y + bb.y;
  ((float2*)outf)[off2+tid] = r;
}

// ---------- fused: x1 = LN(shifted+proj); scan prep; all bf16 I/O ----------
__global__ __launch_bounds__(256) void ln_scan_k(const unsigned int* __restrict__ Ab,
    const unsigned int* __restrict__ Pb,
    const float* __restrict__ g, const float* __restrict__ be, const float* __restrict__ tm,
    unsigned int* __restrict__ x1b, unsigned int* __restrict__ dec, unsigned int* __restrict__ u,
    float* __restrict__ dm, float* __restrict__ es){
  __shared__ float lds[16];
  const size_t row = blockIdx.x;
  const size_t off2 = row * 256;
  const int tid = threadIdx.x;
  unsigned av = Ab[off2+tid], pv = Pb[off2+tid];
  float a0 = blo(av) + blo(pv);
  float a1 = bhi(av) + bhi(pv);
  float s1 = a0+a1, s2 = a0*a0+a1*a1;
  block_sum2(s1, s2, lds);
  float mean = s1 * (1.f/512.f);
  float var  = s2 * (1.f/512.f) - mean*mean;
  float rstd = rsqrtf(var + 1e-5f);
  float2 gg = ((const float2*)g)[tid], bb = ((const float2*)be)[tid], tt = ((const float2*)tm)[tid];
  float r0 = (a0-mean)*rstd*gg.x + bb.x;
  float r1 = (a1-mean)*rstd*gg.y + bb.y;
  x1b[off2+tid] = bpack(r0, r1);
  float dc0 = sigmoidf_(r0*tt.x), dc1 = sigmoidf_(r1*tt.y);
  float e0 = expf(r0), e1 = expf(r1);
  dec[off2+tid] = bpack(dc0, dc1);
  u[off2+tid]   = bpack(e0*r0, e1*r1);
  float dsum = dc0+dc1, esum = e0+e1;
  block_sum2(dsum, esum, lds);
  if (tid==0){ dm[row]=dsum*(1.f/512.f); es[row]=esum; }
}

// ---------- fused: coupled = LN(sigmoid(R)*V); x2 = LN(X1+coupled); bf16 I/O ----------
__global__ __launch_bounds__(256) void ln2x_k(const unsigned int* __restrict__ R,
    const unsigned int* __restrict__ V, const unsigned int* __restrict__ X1,
    const float* __restrict__ g1, const float* __restrict__ b1_,
    const float* __restrict__ g2, const float* __restrict__ b2_,
    unsigned int* __restrict__ x2b){
  __shared__ float lds[16];
  const size_t off2 = (size_t)blockIdx.x * 256;
  const int tid = threadIdx.x;
  unsigned rv = R[off2+tid], vv = V[off2+tid];
  float a0 = sigmoidf_(blo(rv))*blo(vv);
  float a1 = sigmoidf_(bhi(rv))*bhi(vv);
  float s1 = a0+a1, s2 = a0*a0+a1*a1;
  block_sum2(s1, s2, lds);
  float mean = s1*(1.f/512.f);
  float var  = s2*(1.f/512.f) - mean*mean;
  float rstd = rsqrtf(var + 1e-5f);
  float2 g1v = ((const float2*)g1)[tid], b1v = ((const float2*)b1_)[tid];
  float c0 = (a0-mean)*rstd*g1v.x + b1v.x;
  float c1 = (a1-mean)*rstd*g1v.y + b1v.y;
  unsigned x1v = X1[off2+tid];
  float t0 = blo(x1v) + c0, t1 = bhi(x1v) + c1;
  float u1 = t0+t1, u2 = t0*t0+t1*t1;
  block_sum2(u1, u2, lds);
  float mean2 = u1*(1.f/512.f);
  float var2  = u2*(1.f/512.f) - mean2*mean2;
  float rstd2 = rsqrtf(var2 + 1e-5f);
  float2 g2v = ((const float2*)g2)[tid], b2v = ((const float2*)b2_)[tid];
  float r0 = (t0-mean2)*rstd2*g2v.x + b2v.x;
  float r1 = (t1-mean2)*rstd2*g2v.y + b2v.y;
  x2b[off2+tid] = bpack(r0, r1);
}

// ---------- b scan phase 1 (bf16 in, 256 threads, paired) ----------
__global__ __launch_bounds__(256) void bscan_p1(const unsigned int* __restrict__ decay,
    const unsigned int* __restrict__ u, float* __restrict__ Gc, float* __restrict__ Uc){
  const int c = blockIdx.x, b = blockIdx.y, t = threadIdx.x;
  size_t base2 = ((size_t)b*SEQ + (size_t)c*CHUNK)*256 + t;
  float G0=1.f, G1=1.f, U0=0.f, U1=0.f;
  for (int i=0;i<CHUNK;++i){
    unsigned dv = decay[base2 + (size_t)i*256];
    unsigned uv = u[base2 + (size_t)i*256];
    float g0 = blo(dv), g1 = bhi(dv);
    U0 = g0*U0 + blo(uv); G0 *= g0;
    U1 = g1*U1 + bhi(uv); G1 *= g1;
  }
  size_t idx2 = ((size_t)b*NCHUNK + c)*256 + t;
  float2 gv; gv.x=G0; gv.y=G1;
  float2 uv2; uv2.x=U0; uv2.y=U1;
  ((float2*)Gc)[idx2] = gv;
  ((float2*)Uc)[idx2] = uv2;
}

// ---------- merged: b-scan phase 2 (blocks 0-3) + 'a' scan (blocks 4-7) ----------
__global__ __launch_bounds__(512) void scan2_k(const float* __restrict__ Gc, const float* __restrict__ Uc,
    float* __restrict__ binit, const float* __restrict__ dm, const float* __restrict__ es,
    float* __restrict__ a_out){
  __shared__ float sG[512], sU[512];
  if (blockIdx.x < 4){
    const int b = blockIdx.x, d = threadIdx.x;
    float cur = 0.f;
    for (int c=0;c<NCHUNK;++c){
      size_t idx = ((size_t)b*NCHUNK + c)*D_MODEL + d;
      binit[idx] = cur;
      cur = Gc[idx]*cur + Uc[idx];
    }
  } else {
    const int b = blockIdx.x - 4, tid = threadIdx.x;
    const float* dmb = dm + (size_t)b*SEQ;
    const float* esb = es + (size_t)b*SEQ;
    const int t0 = tid*4;
    float gi[4], ui[4];
    #pragma unroll
    for (int i=0;i<4;++i){ gi[i]=dmb[t0+i]; ui[i]=esb[t0+i]; }
    float G=1.f, U=0.f;
    #pragma unroll
    for (int i=0;i<4;++i){ U = gi[i]*U + ui[i]; G *= gi[i]; }
    sG[tid]=G; sU[tid]=U;
    __syncthreads();
    for (int off=1; off<512; off<<=1){
      float pg=1.f, pu=0.f;
      bool act = tid >= off;
      if (act){ pg = sG[tid-off]; pu = sU[tid-off]; }
      __syncthreads();
      if (act){ sU[tid] = sG[tid]*pu + sU[tid]; sG[tid] = sG[tid]*pg; }
      __syncthreads();
    }
    float a = (tid==0) ? 0.f : sU[tid-1];
    #pragma unroll
    for (int i=0;i<4;++i){ a = gi[i]*a + ui[i]; a_out[(size_t)b*SEQ + t0 + i] = a; }
  }
}

// ---------- fused p3 + LN(merged), bf16 I/O, 256 threads paired ----------
__global__ __launch_bounds__(256) void p3ln_k(const unsigned int* __restrict__ decay,
    const unsigned int* __restrict__ u,
    const float* __restrict__ binit, const float* __restrict__ a,
    const float* __restrict__ g, const float* __restrict__ be,
    unsigned int* __restrict__ mb){
  __shared__ float lds[16];
  const int c = blockIdx.x, b = blockIdx.y, t = threadIdx.x;
  size_t base2 = ((size_t)b*SEQ + (size_t)c*CHUNK)*256 + t;
  float2 bv = ((const float2*)binit)[((size_t)b*NCHUNK + c)*256 + t];
  float2 gg = ((const float2*)g)[t], bb = ((const float2*)be)[t];
  for (int i=0;i<CHUNK;++i){
    unsigned dv = decay[base2 + (size_t)i*256];
    unsigned uv = u[base2 + (size_t)i*256];
    bv.x = blo(dv)*bv.x + blo(uv);
    bv.y = bhi(dv)*bv.y + bhi(uv);
    float av = a[(size_t)b*SEQ + (size_t)c*CHUNK + i];
    float inv = 1.f/(av + 1e-8f);
    float v0 = bv.x*inv, v1 = bv.y*inv;
    float s1 = v0+v1, s2 = v0*v0+v1*v1;
    block_sum2(s1, s2, lds);
    float mean = s1*(1.f/512.f);
    float var  = s2*(1.f/512.f) - mean*mean;
    float rstd = rsqrtf(var + 1e-5f);
    mb[base2 + (size_t)i*256] = bpack((v0-mean)*rstd*gg.x + bb.x,
                                      (v1-mean)*rstd*gg.y + bb.y);
  }
}

extern "C" void kernel_launch(void* const* d_in, const int* in_sizes, int n_in,
                              void* d_out, int out_size, void* d_ws, size_t ws_size,
                              hipStream_t stream){
  const float* x     = (const float*)d_in[0];
  const float* xp    = (const float*)d_in[1];
  const float* mu    = (const float*)d_in[2];
  const float* in_w  = (const float*)d_in[3];
  const float* in_b  = (const float*)d_in[4];
  const float* out_w = (const float*)d_in[5];
  const float* out_b = (const float*)d_in[6];
  const float* ln1_g = (const float*)d_in[7];
  const float* ln1_b = (const float*)d_in[8];
  const float* tm    = (const float*)d_in[9];
  const float* sm_g  = (const float*)d_in[10];
  const float* sm_b  = (const float*)d_in[11];
  const float* wr_w  = (const float*)d_in[12];
  const float* wr_b  = (const float*)d_in[13];
  const float* wv_w  = (const float*)d_in[14];
  const float* wv_b  = (const float*)d_in[15];
  const float* sc_g  = (const float*)d_in[16];
  const float* sc_b  = (const float*)d_in[17];
  const float* ln2_g = (const float*)d_in[18];
  const float* ln2_b = (const float*)d_in[19];
  const float* w1    = (const float*)d_in[20];
  const float* b1    = (const float*)d_in[21];
  const float* w2    = (const float*)d_in[22];
  const float* b2    = (const float*)d_in[23];
  const float* ln3_g = (const float*)d_in[24];
  const float* ln3_b = (const float*)d_in[25];
  float* out = (float*)d_out;
  float* ws  = (float*)d_ws;

  const size_t N = (size_t)M_TOK*D_MODEL;   // 4,194,304
  // bf16 buffers carved from the old S0f/S1f fp32 regions:
  unsigned short* Pb  = (unsigned short*)ws;          // proj bf16 (8MB)
  unsigned short* X1b = (unsigned short*)ws + N;      // x1 bf16 (8MB)
  unsigned short* F0  = (unsigned short*)(ws + N);    // ffn2 half0 (8MB)
  unsigned short* F1  = (unsigned short*)(ws + N) + N;// ffn2 half1 (8MB)
  float* EX  = ws + 3*N;
  float* dm    = EX;
  float* es    = EX + 8192;
  float* aarr  = EX + 16384;
  float* Gc    = EX + 24576;
  float* Uc    = Gc + 131072;
  float* binit = Uc + 131072;

  unsigned short* SB = (unsigned short*)(ws + 3*N + N/4);
  unsigned short* Wq = SB;
  unsigned short* Wo = Wq + 786432;
  unsigned short* Wr = Wo + 262144;
  unsigned short* Wv = Wr + 262144;
  unsigned short* W1 = Wv + 262144;
  unsigned short* W2 = W1 + 1048576;
  unsigned short* Xb = W2 + 1048576;       // shifted bf16, later x2 bf16
  unsigned short* Mb = Xb + N;             // merged bf16
  unsigned short* U  = Mb + N;
  unsigned short* Qb  = U;                 // qkv bf16 (24MB)
  unsigned short* AOb = U + 12*1024*1024;  // attn out bf16 (8MB)
  unsigned short* ub   = U;                // after Qb dead
  unsigned short* decb = U + 12*1024*1024; // after AOb dead
  unsigned short* Rb   = U;                // after ub dead
  unsigned short* Vb   = U + 4*1024*1024;
  unsigned short* Hb   = U;                // FFN hidden (32MB)

  // 0. weight converts + shift (bf16 only)
  cvtshift_k<<<7680, 256, 0, stream>>>(in_w, out_w, wr_w, wv_w, w1, w2,
                                       Wq, Wo, Wr, Wv, W1, W2,
                                       x, xp, mu, Xb);
  // 1. qkv -> Qb
  mgemm_k<0,1><<<dim3(12,64), 256, 0, stream>>>(Xb, Wq, in_b, nullptr, Qb, 1536, 512);
  // 2. flash attention -> AOb
  fattn_k<<<dim3(SEQ/128, NH, BATCH), 512, 0, stream>>>(Qb, AOb);
  // 3. out-proj -> Pb (bf16)
  mgemm64_k<0,0,0><<<dim3(8,64), 256, 0, stream>>>(AOb, Wo, nullptr, out_b, nullptr,
                                                   Pb, nullptr, 512, 512);
  // 4. x1 = LN(shifted+proj) -> X1b; decb/ub; dm/es
  ln_scan_k<<<M_TOK, 256, 0, stream>>>((const unsigned int*)Xb, (const unsigned int*)Pb,
                                       ln1_g, ln1_b, tm,
                                       (unsigned int*)X1b, (unsigned int*)decb, (unsigned int*)ub,
                                       dm, es);
  // 5. b-scan phase 1
  bscan_p1<<<dim3(NCHUNK, BATCH), 256, 0, stream>>>((const unsigned int*)decb, (const unsigned int*)ub, Gc, Uc);
  // 6. merged p2 + ascan
  scan2_k<<<8, 512, 0, stream>>>(Gc, Uc, binit, dm, es, aarr);
  // 7. p3 + LN(merged) -> Mb
  p3ln_k<<<dim3(NCHUNK, BATCH), 256, 0, stream>>>((const unsigned int*)decb, (const unsigned int*)ub,
                                                  binit, aarr, sm_g, sm_b, (unsigned int*)Mb);
  // 8. r -> Rb, v -> Vb (bf16, fused)
  mgemm64_k<0,1,0><<<dim3(16,64), 256, 0, stream>>>(Mb, Wr, Wv, wr_b, wv_b,
                                                    Rb, Vb, 512, 512);
  // 9. coupled-LN + x2-LN -> Xb (x2 bf16)
  ln2x_k<<<M_TOK, 256, 0, stream>>>((const unsigned int*)Rb, (const unsigned int*)Vb,
                                    (const unsigned int*)X1b,
                                    sc_g, sc_b, ln2_g, ln2_b, (unsigned int*)Xb);
  // 10. hidden = relu(x2 @ w1.T + b1) -> Hb
  mgemm_k<1,1><<<dim3(16,64), 256, 0, stream>>>(Xb, W1, b1, nullptr, Hb, 2048, 512);
  // 11. ffnout split-K -> F0 (bias) + F1
  mgemm64_k<0,0,1><<<dim3(16,64), 256, 0, stream>>>(Hb, W2, nullptr, b2, nullptr,
                                                    F0, F1, 512, 2048);
  // 12. out = LN(x2 + F0 + F1)
  lnfin_k<<<M_TOK, 256, 0, stream>>>((const unsigned int*)Xb, (const unsigned int*)F0,
                                     (const unsigned int*)F1, ln3_g, ln3_b, out);
}